// Round 1
// baseline (397.170 us; speedup 1.0000x reference)
//
#include <hip/hip_runtime.h>

constexpr int NTOK = 65536;
constexpr int DIM  = 128;
constexpr int NK   = 1024;

__device__ __forceinline__ void fma4(float4& a, float s, float4 b) {
  a.x = fmaf(s, b.x, a.x); a.y = fmaf(s, b.y, a.y);
  a.z = fmaf(s, b.z, a.z); a.w = fmaf(s, b.w, a.w);
}

// ---- zero accumulators (counts, segsum, nflag) ----
__global__ void zero_k(float* __restrict__ counts, float* __restrict__ segsum,
                       int* __restrict__ nflag) {
  int i = blockIdx.x * 256 + threadIdx.x;
  if (i < NK * DIM) segsum[i] = 0.f;
  else if (i < NK * DIM + NK) counts[i - NK * DIM] = 0.f;
  else if (i == NK * DIM + NK) *nflag = 0;
}

// ---- |e_k|^2 ----
__global__ void enorm_k(const float* __restrict__ emb, float* __restrict__ en2) {
  int k = blockIdx.x * 256 + threadIdx.x;
  float acc = 0.f;
  for (int d = 0; d < DIM; d += 4) {
    float4 v = *(const float4*)&emb[k * DIM + d];
    acc += v.x * v.x + v.y * v.y + v.z * v.z + v.w * v.w;
  }
  en2[k] = acc;
}

// ---- main: fused distance + running argmin (+2nd best for f64 fallback flag) ----
// block: 128 threads = (tr 0..7) x (tc 0..15); tile 64 rows x 256 codes, d-chunk 32
// per-thread micro-tile: 8 rows x 16 codes. LDS d-major with XOR swizzle.
__global__ __launch_bounds__(128, 2)
void argmin_k(const float* __restrict__ x, const float* __restrict__ emb,
              const float* __restrict__ en2, int* __restrict__ idx_arr,
              float* __restrict__ out_idx, int* __restrict__ nflag,
              int* __restrict__ flags) {
  __shared__ float es[32 * 256];
  __shared__ float xs[32 * 64];
  const int t   = threadIdx.x;
  const int tr  = t >> 4;
  const int tc  = t & 15;
  const int rbase = blockIdx.x * 64;
  const int tr8 = tr * 8;
  const int tc4 = tc * 4;

  float bestv[8], best2v[8];
  int   besti[8];
#pragma unroll
  for (int i = 0; i < 8; i++) { bestv[i] = 3.0e38f; best2v[i] = 3.0e38f; besti[i] = 0; }

  for (int cc = 0; cc < 4; cc++) {
    float4 acc[8][4];
#pragma unroll
    for (int i = 0; i < 8; i++)
#pragma unroll
      for (int m = 0; m < 4; m++) acc[i][m] = make_float4(0.f, 0.f, 0.f, 0.f);

    for (int dc = 0; dc < 4; dc++) {
      __syncthreads();
      // stage embedding chunk: 256 codes x 32 dims, transposed + swizzled
#pragma unroll
      for (int it = 0; it < 16; it++) {
        int f  = it * 128 + t;
        int c  = f >> 3;
        int d4 = f & 7;
        float4 v = *(const float4*)&emb[(cc * 256 + c) * DIM + dc * 32 + d4 * 4];
        int d0 = d4 * 4;
        es[(d0 + 0) * 256 + (c ^ (((d0 + 0) & 7) << 2))] = v.x;
        es[(d0 + 1) * 256 + (c ^ (((d0 + 1) & 7) << 2))] = v.y;
        es[(d0 + 2) * 256 + (c ^ (((d0 + 2) & 7) << 2))] = v.z;
        es[(d0 + 3) * 256 + (c ^ (((d0 + 3) & 7) << 2))] = v.w;
      }
      // stage x chunk: 64 rows x 32 dims, transposed + swizzled
#pragma unroll
      for (int it = 0; it < 4; it++) {
        int f  = it * 128 + t;
        int r  = f >> 3;
        int d4 = f & 7;
        float4 v = *(const float4*)&x[(rbase + r) * DIM + dc * 32 + d4 * 4];
        int d0 = d4 * 4;
        xs[(d0 + 0) * 64 + (r ^ (((d0 + 0) & 7) << 2))] = v.x;
        xs[(d0 + 1) * 64 + (r ^ (((d0 + 1) & 7) << 2))] = v.y;
        xs[(d0 + 2) * 64 + (r ^ (((d0 + 2) & 7) << 2))] = v.z;
        xs[(d0 + 3) * 64 + (r ^ (((d0 + 3) & 7) << 2))] = v.w;
      }
      __syncthreads();

#pragma unroll 2
      for (int d = 0; d < 32; d++) {
        int s = (d & 7) << 2;
        const float* esd = &es[d * 256];
        const float* xsd = &xs[d * 64];
        int r0 = tr8 ^ s;
        float4 xa = *(const float4*)&xsd[r0];
        float4 xb = *(const float4*)&xsd[r0 ^ 4];
        int c0 = tc4 ^ s;
        float4 e0 = *(const float4*)&esd[c0];
        float4 e1 = *(const float4*)&esd[c0 + 64];
        float4 e2 = *(const float4*)&esd[c0 + 128];
        float4 e3 = *(const float4*)&esd[c0 + 192];
        float xv[8] = {xa.x, xa.y, xa.z, xa.w, xb.x, xb.y, xb.z, xb.w};
#pragma unroll
        for (int i = 0; i < 8; i++) {
          fma4(acc[i][0], xv[i], e0);
          fma4(acc[i][1], xv[i], e1);
          fma4(acc[i][2], xv[i], e2);
          fma4(acc[i][3], xv[i], e3);
        }
      }
    }
    // fold |e|^2, update running best/second-best
#pragma unroll
    for (int m = 0; m < 4; m++) {
      int cb = cc * 256 + m * 64 + tc4;
      float4 e2v = *(const float4*)&en2[cb];
      float nrm[4] = {e2v.x, e2v.y, e2v.z, e2v.w};
#pragma unroll
      for (int i = 0; i < 8; i++) {
        float a4[4] = {acc[i][m].x, acc[i][m].y, acc[i][m].z, acc[i][m].w};
#pragma unroll
        for (int j = 0; j < 4; j++) {
          float sc = fmaf(-2.f, a4[j], nrm[j]);
          if (sc < bestv[i]) { best2v[i] = bestv[i]; bestv[i] = sc; besti[i] = cb + j; }
          else if (sc < best2v[i]) best2v[i] = sc;
        }
      }
    }
  }
  // reduce across the 16 tc lanes (lane bits 0..3); tie-break -> smaller index
#pragma unroll
  for (int i = 0; i < 8; i++) {
    float bv = bestv[i], b2 = best2v[i];
    int bi = besti[i];
    for (int mask = 1; mask < 16; mask <<= 1) {
      float ov = __shfl_xor(bv, mask);
      int   oi = __shfl_xor(bi, mask);
      float o2 = __shfl_xor(b2, mask);
      float hi = fmaxf(bv, ov);
      b2 = fminf(fminf(b2, o2), hi);
      if (ov < bv || (ov == bv && oi < bi)) { bv = ov; bi = oi; }
    }
    if (tc == 0) {
      int row = rbase + tr8 + i;
      idx_arr[row] = bi;
      out_idx[row] = (float)bi;
      if (b2 - bv < 1e-4f) { int p = atomicAdd(nflag, 1); flags[p] = row; }
    }
  }
}

// ---- exact f64 recompute for near-tie rows ----
__global__ void fb_k(const float* __restrict__ x, const float* __restrict__ emb,
                     const int* __restrict__ nflag, const int* __restrict__ flags,
                     int* __restrict__ idx_arr, float* __restrict__ out_idx) {
  int n = *nflag;
  __shared__ double xsh[DIM];
  __shared__ double sv[256];
  __shared__ int    si[256];
  for (int f = blockIdx.x; f < n; f += gridDim.x) {
    int row = flags[f];
    __syncthreads();
    if (threadIdx.x < DIM) xsh[threadIdx.x] = (double)x[row * DIM + threadIdx.x];
    __syncthreads();
    double bv = 1e300; int bi = 0;
    for (int q = 0; q < 4; q++) {
      int c = threadIdx.x * 4 + q;
      double ee = 0.0, xe = 0.0;
      for (int d = 0; d < DIM; d++) {
        double e = (double)emb[c * DIM + d];
        ee = fma(e, e, ee);
        xe = fma(xsh[d], e, xe);
      }
      double s = ee - 2.0 * xe;
      if (s < bv || (s == bv && c < bi)) { bv = s; bi = c; }
    }
    sv[threadIdx.x] = bv; si[threadIdx.x] = bi;
    __syncthreads();
    for (int s2 = 128; s2 > 0; s2 >>= 1) {
      if ((int)threadIdx.x < s2) {
        double ov = sv[threadIdx.x + s2]; int oi = si[threadIdx.x + s2];
        if (ov < sv[threadIdx.x] || (ov == sv[threadIdx.x] && oi < si[threadIdx.x])) {
          sv[threadIdx.x] = ov; si[threadIdx.x] = oi;
        }
      }
      __syncthreads();
    }
    if (threadIdx.x == 0) { idx_arr[row] = si[0]; out_idx[row] = (float)si[0]; }
  }
}

// ---- gather quantized, loss partials, counts, segment sums ----
__global__ void gather_k(const float* __restrict__ x, const float* __restrict__ emb,
                         const int* __restrict__ idx_arr, float* __restrict__ out_q,
                         float* __restrict__ counts, float* __restrict__ segsum,
                         float* __restrict__ partials) {
  int t = threadIdx.x;
  int w = t >> 6;
  int lane = t & 63;
  float lsum = 0.f;
  for (int it = 0; it < 8; it++) {
    int row = (it * 2048 + blockIdx.x) * 4 + w;
    int k = idx_arr[row];
    float2 q  = *(const float2*)&emb[k * DIM + lane * 2];
    float2 xv = *(const float2*)&x[row * DIM + lane * 2];
    *(float2*)&out_q[row * DIM + lane * 2] = q;
    float d0 = q.x - xv.x, d1 = q.y - xv.y;
    lsum += d0 * d0 + d1 * d1;
    if (lane == 0) atomicAdd(&counts[k], 1.0f);
    atomicAdd(&segsum[k * DIM + lane * 2 + 0], xv.x);
    atomicAdd(&segsum[k * DIM + lane * 2 + 1], xv.y);
  }
  __shared__ float red[256];
  red[t] = lsum;
  __syncthreads();
  for (int s = 128; s > 0; s >>= 1) {
    if (t < s) red[t] += red[t + s];
    __syncthreads();
  }
  if (t == 0) partials[blockIdx.x] = red[0];
}

// ---- loss + cluster-size EMA + csk (single block, deterministic) ----
__global__ void fin_k(const float* __restrict__ cluster_size, const float* __restrict__ counts,
                      const float* __restrict__ partials, float* __restrict__ out_loss,
                      float* __restrict__ out_ncs, float* __restrict__ csk) {
  __shared__ float red[1024];
  int t = threadIdx.x;
  red[t] = partials[t] + partials[t + 1024];
  __syncthreads();
  for (int s = 512; s > 0; s >>= 1) {
    if (t < s) red[t] += red[t + s];
    __syncthreads();
  }
  float S = red[0];
  __syncthreads();
  if (t == 0) out_loss[0] = 2.0f * S / 8388608.0f;  // loss = diff2 + 1.0*diff2
  float ncs = cluster_size[t] * 0.99f + 0.01f * counts[t];
  out_ncs[t] = ncs;
  red[t] = ncs;
  __syncthreads();
  for (int s = 512; s > 0; s >>= 1) {
    if (t < s) red[t] += red[t + s];
    __syncthreads();
  }
  float n = red[0];
  csk[t] = (ncs + 1e-5f) / (n + 1024.0f * 1e-5f) * n;
}

// ---- embed_avg EMA + new embedding ----
__global__ void emb_k(const float* __restrict__ embed_avg, const float* __restrict__ segsum,
                      const float* __restrict__ csk, float* __restrict__ out_nemb,
                      float* __restrict__ out_nea) {
  int i = blockIdx.x * 256 + threadIdx.x;
  float na = embed_avg[i] * 0.99f + 0.01f * segsum[i];
  out_nea[i] = na;
  out_nemb[i] = na / csk[i >> 7];
}

extern "C" void kernel_launch(void* const* d_in, const int* in_sizes, int n_in,
                              void* d_out, int out_size, void* d_ws, size_t ws_size,
                              hipStream_t stream) {
  const float* x   = (const float*)d_in[0];
  const float* emb = (const float*)d_in[1];
  const float* cs  = (const float*)d_in[2];
  const float* ea  = (const float*)d_in[3];

  float* out      = (float*)d_out;
  float* out_q    = out;                      // [65536,128]
  float* out_loss = out + 8388608;            // scalar
  float* out_idx  = out + 8388609;            // [65536] (as float)
  float* out_nemb = out + 8454145;            // [1024,128]
  float* out_ncs  = out + 8585217;            // [1024]
  float* out_nea  = out + 8586241;            // [1024,128]

  float* W        = (float*)d_ws;
  float* en2      = W;                        // 1024
  float* counts   = W + 1024;                 // 1024
  float* segsum   = W + 2048;                 // 131072
  float* csk      = W + 133120;               // 1024
  float* partials = W + 134144;               // 2048
  int*   nflag    = (int*)(W + 136192);       // 1
  int*   flags    = (int*)(W + 136208);       // 65536
  int*   idx_arr  = (int*)(W + 136208 + 65536); // 65536

  zero_k<<<517, 256, 0, stream>>>(counts, segsum, nflag);
  enorm_k<<<4, 256, 0, stream>>>(emb, en2);
  argmin_k<<<1024, 128, 0, stream>>>(x, emb, en2, idx_arr, out_idx, nflag, flags);
  fb_k<<<1024, 256, 0, stream>>>(x, emb, nflag, flags, idx_arr, out_idx);
  gather_k<<<2048, 256, 0, stream>>>(x, emb, idx_arr, out_q, counts, segsum, partials);
  fin_k<<<1, 1024, 0, stream>>>(cs, counts, partials, out_loss, out_ncs, csk);
  emb_k<<<512, 256, 0, stream>>>(ea, segsum, csk, out_nemb, out_nea);
}

// Round 3
// 312.570 us; speedup vs baseline: 1.2707x; 1.2707x over previous
//
#include <hip/hip_runtime.h>

typedef __attribute__((ext_vector_type(8))) short short8;
typedef __attribute__((ext_vector_type(4))) float f32x4;

constexpr int NTOK = 65536;
constexpr int DIM  = 128;
constexpr int NK   = 1024;

__device__ __forceinline__ unsigned short f2bf(float f) {
  unsigned int u = __float_as_uint(f);
  unsigned int r = u + 0x7fffu + ((u >> 16) & 1u);
  return (unsigned short)(r >> 16);
}
__device__ __forceinline__ float bf2f(unsigned short h) {
  return __uint_as_float(((unsigned int)h) << 16);
}

// ---- B prep: emb f32 [1024][128] -> bf16 hi|lo packed [1024][256]; also nflag=0 ----
__global__ void bprep_k(const float* __restrict__ emb, unsigned short* __restrict__ bp,
                        int* __restrict__ nflag) {
  int i = blockIdx.x * 256 + threadIdx.x;   // 0..32767
  if (i == 0) *nflag = 0;
  int code = i >> 5;
  int d = (i & 31) * 4;
  float4 v = *(const float4*)&emb[code * 128 + d];
  float vf[4] = {v.x, v.y, v.z, v.w};
  unsigned int uh[2], ul[2];
  unsigned short h[4], l[4];
#pragma unroll
  for (int j = 0; j < 4; j++) {
    h[j] = f2bf(vf[j]);
    l[j] = f2bf(vf[j] - bf2f(h[j]));
  }
  uh[0] = (unsigned int)h[0] | ((unsigned int)h[1] << 16);
  uh[1] = (unsigned int)h[2] | ((unsigned int)h[3] << 16);
  ul[0] = (unsigned int)l[0] | ((unsigned int)l[1] << 16);
  ul[1] = (unsigned int)l[2] | ((unsigned int)l[3] << 16);
  *(uint2*)&bp[code * 256 + d] = make_uint2(uh[0], uh[1]);
  *(uint2*)&bp[code * 256 + 128 + d] = make_uint2(ul[0], ul[1]);
}

// ---- |e_k|^2 in f64 (exact for fallback) + f32 (for scores) ----
__global__ void enorm_k(const float* __restrict__ emb, float* __restrict__ en2,
                        double* __restrict__ en2d) {
  int k = blockIdx.x * 256 + threadIdx.x;
  double acc = 0.0;
  for (int d = 0; d < DIM; d += 4) {
    float4 v = *(const float4*)&emb[k * DIM + d];
    acc = fma((double)v.x, (double)v.x, acc);
    acc = fma((double)v.y, (double)v.y, acc);
    acc = fma((double)v.z, (double)v.z, acc);
    acc = fma((double)v.w, (double)v.w, acc);
  }
  en2[k] = (float)acc;
  en2d[k] = acc;
}

// ---- main: MFMA bf16-split distance + running argmin ----
// 512 blocks x 256 thr (4 waves). BM=128 rows/block, wave tile 32 rows x 64 cols.
// a-frags (x hi/lo) register-resident; LDS reused: x staging then B chunks.
__global__ __launch_bounds__(256, 2)
void argmin_k(const float* __restrict__ x, const unsigned short* __restrict__ bp,
              const float* __restrict__ en2, int* __restrict__ idx_arr,
              float* __restrict__ out_idx, int* __restrict__ nflag,
              int* __restrict__ flags) {
  __shared__ __align__(16) char smem[65536];
  const int t    = threadIdx.x;
  const int lane = t & 63;
  const int w    = t >> 6;
  const int l15  = lane & 15;
  const int lo4  = lane >> 4;
  const int rbase = blockIdx.x * 128;

  // stage x -> LDS as bf16 hi|lo, row-major 512B/row, XOR swizzle
  // 128 rows x 128 dims = 16384 floats; 256 thr x 8 floats x 8 iters
#pragma unroll
  for (int i = 0; i < 8; i++) {
    int f = i * 2048 + t * 8;
    int row = f >> 7;
    int d = f & 127;
    const float* xp = &x[(rbase + row) * 128 + d];
    float4 v0 = *(const float4*)xp;
    float4 v1 = *(const float4*)(xp + 4);
    float vf[8] = {v0.x, v0.y, v0.z, v0.w, v1.x, v1.y, v1.z, v1.w};
    unsigned short hh[8], ll[8];
#pragma unroll
    for (int j = 0; j < 8; j++) {
      hh[j] = f2bf(vf[j]);
      ll[j] = f2bf(vf[j] - bf2f(hh[j]));
    }
    uint4 hv, lv;
    hv.x = (unsigned)hh[0] | ((unsigned)hh[1] << 16); hv.y = (unsigned)hh[2] | ((unsigned)hh[3] << 16);
    hv.z = (unsigned)hh[4] | ((unsigned)hh[5] << 16); hv.w = (unsigned)hh[6] | ((unsigned)hh[7] << 16);
    lv.x = (unsigned)ll[0] | ((unsigned)ll[1] << 16); lv.y = (unsigned)ll[2] | ((unsigned)ll[3] << 16);
    lv.z = (unsigned)ll[4] | ((unsigned)ll[5] << 16); lv.w = (unsigned)ll[6] | ((unsigned)ll[7] << 16);
    int sw = (row & 7) << 4;
    int byteH = row * 512 + d * 2;
    *(uint4*)&smem[byteH ^ sw] = hv;
    *(uint4*)&smem[(byteH + 256) ^ sw] = lv;
  }
  __syncthreads();

  // a-frags -> registers (reused for every code chunk)
  short8 ah[2][4], al[2][4];
#pragma unroll
  for (int m = 0; m < 2; m++)
#pragma unroll
    for (int kk = 0; kk < 4; kk++) {
      int row = w * 32 + m * 16 + l15;
      int sw = (row & 7) << 4;
      int byte_ = row * 512 + kk * 64 + (lo4 << 4);
      ah[m][kk] = *(short8*)&smem[byte_ ^ sw];
      al[m][kk] = *(short8*)&smem[(byte_ + 256) ^ sw];
    }

  float bv[2][4], b2[2][4];
  int bi[2][4];
#pragma unroll
  for (int m = 0; m < 2; m++)
#pragma unroll
    for (int r = 0; r < 4; r++) { bv[m][r] = 3.0e38f; b2[m][r] = 3.0e38f; bi[m][r] = 0; }

  const uint4* bp4 = (const uint4*)bp;
  uint4 R[8];
#pragma unroll
  for (int u = 0; u < 8; u++) R[u] = bp4[u * 256 + t];   // chunk 0 prefetch

  for (int cg = 0; cg < 16; cg++) {
    __syncthreads();                        // prior chunk fully consumed
#pragma unroll
    for (int u = 0; u < 8; u++) {
      int un = u * 256 + t;
      int code_l = un >> 5;
      int byte_ = code_l * 512 + (un & 31) * 16;
      *(uint4*)&smem[byte_ ^ ((code_l & 7) << 4)] = R[u];
    }
    __syncthreads();
    if (cg < 15) {
#pragma unroll
      for (int u = 0; u < 8; u++) R[u] = bp4[(cg + 1) * 2048 + u * 256 + t];
    }

    f32x4 acc[2][4];
#pragma unroll
    for (int m = 0; m < 2; m++)
#pragma unroll
      for (int n = 0; n < 4; n++) acc[m][n] = (f32x4)(0.0f);

#pragma unroll
    for (int kk = 0; kk < 4; kk++) {
      short8 bh[4], bl[4];
#pragma unroll
      for (int n = 0; n < 4; n++) {
        int code_l = n * 16 + l15;
        int sw = (code_l & 7) << 4;
        int byte_ = code_l * 512 + kk * 64 + (lo4 << 4);
        bh[n] = *(short8*)&smem[byte_ ^ sw];
        bl[n] = *(short8*)&smem[(byte_ + 256) ^ sw];
      }
#pragma unroll
      for (int m = 0; m < 2; m++)
#pragma unroll
        for (int n = 0; n < 4; n++) {
          acc[m][n] = __builtin_amdgcn_mfma_f32_16x16x32_bf16(ah[m][kk], bh[n], acc[m][n], 0, 0, 0);
          acc[m][n] = __builtin_amdgcn_mfma_f32_16x16x32_bf16(ah[m][kk], bl[n], acc[m][n], 0, 0, 0);
          acc[m][n] = __builtin_amdgcn_mfma_f32_16x16x32_bf16(al[m][kk], bh[n], acc[m][n], 0, 0, 0);
        }
    }

    // fold |e|^2 - 2*dot, update running best / 2nd-best
#pragma unroll
    for (int n = 0; n < 4; n++) {
      int col = cg * 64 + n * 16 + l15;
      float e2 = en2[col];
#pragma unroll
      for (int m = 0; m < 2; m++)
#pragma unroll
        for (int r = 0; r < 4; r++) {
          float sc = fmaf(-2.0f, acc[m][n][r], e2);
          if (sc < bv[m][r]) { b2[m][r] = bv[m][r]; bv[m][r] = sc; bi[m][r] = col; }
          else if (sc < b2[m][r]) b2[m][r] = sc;
        }
    }
  }

  // reduce over the 16 column-lanes (lane bits 0..3); tie-break smaller index
#pragma unroll
  for (int m = 0; m < 2; m++)
#pragma unroll
    for (int r = 0; r < 4; r++) {
      float v = bv[m][r], v2 = b2[m][r];
      int ii = bi[m][r];
      for (int mask = 1; mask < 16; mask <<= 1) {
        float ov = __shfl_xor(v, mask);
        float o2 = __shfl_xor(v2, mask);
        int   oi = __shfl_xor(ii, mask);
        float hi = fmaxf(v, ov);
        v2 = fminf(fminf(v2, o2), hi);
        if (ov < v || (ov == v && oi < ii)) { v = ov; ii = oi; }
      }
      if (l15 == 0) {
        int row = rbase + w * 32 + m * 16 + lo4 * 4 + r;
        idx_arr[row] = ii;
        out_idx[row] = (float)ii;
        if (v2 - v < 1.5e-3f) { int p = atomicAdd(nflag, 1); flags[p] = row; }
      }
    }
}

// ---- exact f64 recompute for near-tie rows ----
__global__ void fb_k(const float* __restrict__ x, const float* __restrict__ emb,
                     const double* __restrict__ en2d, const int* __restrict__ nflag,
                     const int* __restrict__ flags, int* __restrict__ idx_arr,
                     float* __restrict__ out_idx) {
  int n = *nflag;
  __shared__ double xsh[DIM];
  __shared__ double sv[256];
  __shared__ int    si[256];
  for (int f = blockIdx.x; f < n; f += gridDim.x) {
    int row = flags[f];
    __syncthreads();
    if (threadIdx.x < DIM) xsh[threadIdx.x] = (double)x[row * DIM + threadIdx.x];
    __syncthreads();
    double bvv = 1e300; int bii = 0;
    for (int q = 0; q < 4; q++) {
      int c = threadIdx.x * 4 + q;
      double xe = 0.0;
      for (int d = 0; d < DIM; d++) xe = fma((double)emb[c * DIM + d], xsh[d], xe);
      double s = en2d[c] - 2.0 * xe;
      if (s < bvv || (s == bvv && c < bii)) { bvv = s; bii = c; }
    }
    sv[threadIdx.x] = bvv; si[threadIdx.x] = bii;
    __syncthreads();
    for (int s2 = 128; s2 > 0; s2 >>= 1) {
      if ((int)threadIdx.x < s2) {
        double ov = sv[threadIdx.x + s2]; int oi = si[threadIdx.x + s2];
        if (ov < sv[threadIdx.x] || (ov == sv[threadIdx.x] && oi < si[threadIdx.x])) {
          sv[threadIdx.x] = ov; si[threadIdx.x] = oi;
        }
      }
      __syncthreads();
    }
    if (threadIdx.x == 0) { idx_arr[row] = si[0]; out_idx[row] = (float)si[0]; }
  }
}

// ---- zero counts + segsum (after argmin: segsum region aliases B_pack) ----
__global__ void zero2_k(float* __restrict__ counts, float* __restrict__ segsum) {
  int i = blockIdx.x * 256 + threadIdx.x;
  if (i < NK * DIM) segsum[i] = 0.f;
  else if (i < NK * DIM + NK) counts[i - NK * DIM] = 0.f;
}

// ---- gather quantized, loss partials, counts, segment sums ----
__global__ void gather_k(const float* __restrict__ x, const float* __restrict__ emb,
                         const int* __restrict__ idx_arr, float* __restrict__ out_q,
                         float* __restrict__ counts, float* __restrict__ segsum,
                         float* __restrict__ partials) {
  int t = threadIdx.x;
  int w = t >> 6;
  int lane = t & 63;
  float lsum = 0.f;
  for (int it = 0; it < 8; it++) {
    int row = (it * 2048 + blockIdx.x) * 4 + w;
    int k = idx_arr[row];
    float2 q  = *(const float2*)&emb[k * DIM + lane * 2];
    float2 xv = *(const float2*)&x[row * DIM + lane * 2];
    *(float2*)&out_q[row * DIM + lane * 2] = q;
    float d0 = q.x - xv.x, d1 = q.y - xv.y;
    lsum += d0 * d0 + d1 * d1;
    if (lane == 0) atomicAdd(&counts[k], 1.0f);
    atomicAdd(&segsum[k * DIM + lane * 2 + 0], xv.x);
    atomicAdd(&segsum[k * DIM + lane * 2 + 1], xv.y);
  }
  __shared__ float red[256];
  red[t] = lsum;
  __syncthreads();
  for (int s = 128; s > 0; s >>= 1) {
    if (t < s) red[t] += red[t + s];
    __syncthreads();
  }
  if (t == 0) partials[blockIdx.x] = red[0];
}

// ---- loss + cluster-size EMA + csk ----
__global__ void fin_k(const float* __restrict__ cluster_size, const float* __restrict__ counts,
                      const float* __restrict__ partials, float* __restrict__ out_loss,
                      float* __restrict__ out_ncs, float* __restrict__ csk) {
  __shared__ float red[1024];
  int t = threadIdx.x;
  red[t] = partials[t] + partials[t + 1024];
  __syncthreads();
  for (int s = 512; s > 0; s >>= 1) {
    if (t < s) red[t] += red[t + s];
    __syncthreads();
  }
  float S = red[0];
  __syncthreads();
  if (t == 0) out_loss[0] = 2.0f * S / 8388608.0f;
  float ncs = cluster_size[t] * 0.99f + 0.01f * counts[t];
  out_ncs[t] = ncs;
  red[t] = ncs;
  __syncthreads();
  for (int s = 512; s > 0; s >>= 1) {
    if (t < s) red[t] += red[t + s];
    __syncthreads();
  }
  float n = red[0];
  csk[t] = (ncs + 1e-5f) / (n + 1024.0f * 1e-5f) * n;
}

// ---- embed_avg EMA + new embedding ----
__global__ void emb_k(const float* __restrict__ embed_avg, const float* __restrict__ segsum,
                      const float* __restrict__ csk, float* __restrict__ out_nemb,
                      float* __restrict__ out_nea) {
  int i = blockIdx.x * 256 + threadIdx.x;
  float na = embed_avg[i] * 0.99f + 0.01f * segsum[i];
  out_nea[i] = na;
  out_nemb[i] = na / csk[i >> 7];
}

extern "C" void kernel_launch(void* const* d_in, const int* in_sizes, int n_in,
                              void* d_out, int out_size, void* d_ws, size_t ws_size,
                              hipStream_t stream) {
  const float* x   = (const float*)d_in[0];
  const float* emb = (const float*)d_in[1];
  const float* cs  = (const float*)d_in[2];
  const float* ea  = (const float*)d_in[3];

  float* out      = (float*)d_out;
  float* out_q    = out;                      // [65536,128]
  float* out_loss = out + 8388608;            // scalar
  float* out_idx  = out + 8388609;            // [65536]
  float* out_nemb = out + 8454145;            // [1024,128]
  float* out_ncs  = out + 8585217;            // [1024]
  float* out_nea  = out + 8586241;            // [1024,128]

  float* W        = (float*)d_ws;
  float* en2      = W;                          // 1024
  float* counts   = W + 1024;                   // 1024
  float* segsum   = W + 2048;                   // 131072 (aliases B_pack)
  unsigned short* bpack = (unsigned short*)(W + 2048);  // 262144 ushort = same 512KB
  float* csk      = W + 133120;                 // 1024
  float* partials = W + 134144;                 // 2048
  int*   nflag    = (int*)(W + 136192);         // 1
  int*   flags    = (int*)(W + 136208);         // 65536
  int*   idx_arr  = (int*)(W + 136208 + 65536); // 65536
  double* en2d    = (double*)(W + 267280);      // 1024 doubles

  bprep_k<<<128, 256, 0, stream>>>(emb, bpack, nflag);
  enorm_k<<<4, 256, 0, stream>>>(emb, en2, en2d);
  argmin_k<<<512, 256, 0, stream>>>(x, bpack, en2, idx_arr, out_idx, nflag, flags);
  fb_k<<<1024, 256, 0, stream>>>(x, emb, en2d, nflag, flags, idx_arr, out_idx);
  zero2_k<<<516, 256, 0, stream>>>(counts, segsum);
  gather_k<<<2048, 256, 0, stream>>>(x, emb, idx_arr, out_q, counts, segsum, partials);
  fin_k<<<1, 1024, 0, stream>>>(cs, counts, partials, out_loss, out_ncs, csk);
  emb_k<<<512, 256, 0, stream>>>(ea, segsum, csk, out_nemb, out_nea);
}

// Round 4
// 271.788 us; speedup vs baseline: 1.4613x; 1.1501x over previous
//
#include <hip/hip_runtime.h>

typedef __attribute__((ext_vector_type(8))) short short8;
typedef __attribute__((ext_vector_type(4))) float f32x4;

constexpr int NTOK = 65536;
constexpr int DIM  = 128;
constexpr int NK   = 1024;

__device__ __forceinline__ unsigned short f2bf(float f) {
  unsigned int u = __float_as_uint(f);
  unsigned int r = u + 0x7fffu + ((u >> 16) & 1u);
  return (unsigned short)(r >> 16);
}
__device__ __forceinline__ float bf2f(unsigned short h) {
  return __uint_as_float(((unsigned int)h) << 16);
}
__device__ __forceinline__ void gload_lds16(const void* g, void* l) {
  __builtin_amdgcn_global_load_lds(
      (const __attribute__((address_space(1))) unsigned int*)g,
      (__attribute__((address_space(3))) unsigned int*)l, 16, 0, 0);
}

// ---- B prep: emb f32 [1024][128] -> pre-swizzled LDS-image bf16 hi|lo chunks ----
// image: chunk cg (64 codes): code_l row of 512B: [ (g*16)^sw : hi 16B ][ +256 : lo 16B ]
// also zeroes nflag and icounts.
__global__ void bprep_k(const float* __restrict__ emb, char* __restrict__ bp,
                        int* __restrict__ nflag, unsigned* __restrict__ icounts) {
  int i = blockIdx.x * 256 + threadIdx.x;   // 0..16383
  if (i == 0) *nflag = 0;
  if (i < NK) icounts[i] = 0u;
  int c = i >> 4;          // code 0..1023
  int g = i & 15;          // dim group (8 dims each)
  float4 v0 = *(const float4*)&emb[c * 128 + g * 8];
  float4 v1 = *(const float4*)&emb[c * 128 + g * 8 + 4];
  float vf[8] = {v0.x, v0.y, v0.z, v0.w, v1.x, v1.y, v1.z, v1.w};
  unsigned short hh[8], ll[8];
#pragma unroll
  for (int j = 0; j < 8; j++) {
    hh[j] = f2bf(vf[j]);
    ll[j] = f2bf(vf[j] - bf2f(hh[j]));
  }
  uint4 hv, lv;
  hv.x = (unsigned)hh[0] | ((unsigned)hh[1] << 16); hv.y = (unsigned)hh[2] | ((unsigned)hh[3] << 16);
  hv.z = (unsigned)hh[4] | ((unsigned)hh[5] << 16); hv.w = (unsigned)hh[6] | ((unsigned)hh[7] << 16);
  lv.x = (unsigned)ll[0] | ((unsigned)ll[1] << 16); lv.y = (unsigned)ll[2] | ((unsigned)ll[3] << 16);
  lv.z = (unsigned)ll[4] | ((unsigned)ll[5] << 16); lv.w = (unsigned)ll[6] | ((unsigned)ll[7] << 16);
  int cg = c >> 6, cl = c & 63;
  int sw = (cl & 7) << 4;
  char* base = bp + cg * 32768 + cl * 512;
  *(uint4*)(base + ((g * 16) ^ sw)) = hv;
  *(uint4*)(base + 256 + ((g * 16) ^ sw)) = lv;
}

// ---- |e_k|^2 in f64 (exact, for fallback) + f32 (for scores) ----
__global__ void enorm_k(const float* __restrict__ emb, float* __restrict__ en2,
                        double* __restrict__ en2d) {
  int k = blockIdx.x * 256 + threadIdx.x;
  double acc = 0.0;
  for (int d = 0; d < DIM; d += 4) {
    float4 v = *(const float4*)&emb[k * DIM + d];
    acc = fma((double)v.x, (double)v.x, acc);
    acc = fma((double)v.y, (double)v.y, acc);
    acc = fma((double)v.z, (double)v.z, acc);
    acc = fma((double)v.w, (double)v.w, acc);
  }
  en2[k] = (float)acc;
  en2d[k] = acc;
}

// ---- main: MFMA bf16-split distance + running argmin ----
// 512 blocks x 256 thr (4 waves). BM=128 rows, wave tile 32 rows x 64 cols.
// A-frags register-resident; B chunks staged via global_load_lds into 2x32KB dbuf.
__global__ __launch_bounds__(256, 2)
void argmin_k(const float* __restrict__ x, const char* __restrict__ bp,
              const float* __restrict__ en2, int* __restrict__ idx_arr,
              float* __restrict__ out_idx, int* __restrict__ nflag,
              int* __restrict__ flags) {
  __shared__ __align__(16) char smem[65536];
  const int t    = threadIdx.x;
  const int lane = t & 63;
  const int w    = t >> 6;
  const int l15  = lane & 15;
  const int lo4  = lane >> 4;
  const int rbase = blockIdx.x * 128;

  // stage x -> LDS as bf16 hi|lo, row-major 512B/row, XOR swizzle (one-time)
#pragma unroll
  for (int i = 0; i < 8; i++) {
    int f = i * 2048 + t * 8;
    int row = f >> 7;
    int d = f & 127;
    const float* xp = &x[(rbase + row) * 128 + d];
    float4 v0 = *(const float4*)xp;
    float4 v1 = *(const float4*)(xp + 4);
    float vf[8] = {v0.x, v0.y, v0.z, v0.w, v1.x, v1.y, v1.z, v1.w};
    unsigned short hh[8], ll[8];
#pragma unroll
    for (int j = 0; j < 8; j++) {
      hh[j] = f2bf(vf[j]);
      ll[j] = f2bf(vf[j] - bf2f(hh[j]));
    }
    uint4 hv, lv;
    hv.x = (unsigned)hh[0] | ((unsigned)hh[1] << 16); hv.y = (unsigned)hh[2] | ((unsigned)hh[3] << 16);
    hv.z = (unsigned)hh[4] | ((unsigned)hh[5] << 16); hv.w = (unsigned)hh[6] | ((unsigned)hh[7] << 16);
    lv.x = (unsigned)ll[0] | ((unsigned)ll[1] << 16); lv.y = (unsigned)ll[2] | ((unsigned)ll[3] << 16);
    lv.z = (unsigned)ll[4] | ((unsigned)ll[5] << 16); lv.w = (unsigned)ll[6] | ((unsigned)ll[7] << 16);
    int sw = (row & 7) << 4;
    int byteH = row * 512 + d * 2;
    *(uint4*)&smem[byteH ^ sw] = hv;
    *(uint4*)&smem[(byteH + 256) ^ sw] = lv;
  }
  __syncthreads();

  // A-frags -> registers (reused for every code chunk)
  short8 ah[2][4], al[2][4];
#pragma unroll
  for (int m = 0; m < 2; m++)
#pragma unroll
    for (int kk = 0; kk < 4; kk++) {
      int row = w * 32 + m * 16 + l15;
      int sw = (row & 7) << 4;
      int byte_ = row * 512 + kk * 64 + (lo4 << 4);
      ah[m][kk] = *(short8*)&smem[byte_ ^ sw];
      al[m][kk] = *(short8*)&smem[(byte_ + 256) ^ sw];
    }
  __syncthreads();   // all waves done reading x region before B staging overwrites

  float bv[2][4], b2[2][4];
  int bi[2][4];
#pragma unroll
  for (int m = 0; m < 2; m++)
#pragma unroll
    for (int r = 0; r < 4; r++) { bv[m][r] = 3.0e38f; b2[m][r] = 3.0e38f; bi[m][r] = 0; }

  // stage chunk 0 into buf0 (each wave stages its 8KB quarter, linear copy)
  {
    const char* gsrc = bp + w * 8192 + lane * 16;
    char* ldst = smem + w * 8192;
#pragma unroll
    for (int u = 0; u < 8; u++) gload_lds16(gsrc + u * 1024, ldst + u * 1024);
  }
  __syncthreads();   // drains vmcnt -> chunk 0 resident

  int cur = 0;
  for (int cg = 0; cg < 16; cg++) {
    // issue next chunk's loads into the other buffer (hidden under compute)
    if (cg < 15) {
      const char* gsrc = bp + (cg + 1) * 32768 + w * 8192 + lane * 16;
      char* ldst = smem + (cur ^ 1) * 32768 + w * 8192;
#pragma unroll
      for (int u = 0; u < 8; u++) gload_lds16(gsrc + u * 1024, ldst + u * 1024);
    }

    // prefetch |e|^2 for this chunk's columns
    float e2r[4];
#pragma unroll
    for (int n = 0; n < 4; n++) e2r[n] = en2[cg * 64 + n * 16 + l15];

    f32x4 acc[2][4];
#pragma unroll
    for (int m = 0; m < 2; m++)
#pragma unroll
      for (int n = 0; n < 4; n++) acc[m][n] = (f32x4)(0.0f);

    const int bufb = cur * 32768;
#pragma unroll
    for (int kk = 0; kk < 4; kk++) {
      short8 bh[4], bl[4];
#pragma unroll
      for (int n = 0; n < 4; n++) {
        int code_l = n * 16 + l15;
        int sw = (code_l & 7) << 4;
        int byte_ = code_l * 512 + kk * 64 + (lo4 << 4);
        bh[n] = *(short8*)&smem[bufb + (byte_ ^ sw)];
        bl[n] = *(short8*)&smem[bufb + ((byte_ + 256) ^ sw)];
      }
#pragma unroll
      for (int m = 0; m < 2; m++)
#pragma unroll
        for (int n = 0; n < 4; n++) {
          acc[m][n] = __builtin_amdgcn_mfma_f32_16x16x32_bf16(ah[m][kk], bh[n], acc[m][n], 0, 0, 0);
          acc[m][n] = __builtin_amdgcn_mfma_f32_16x16x32_bf16(ah[m][kk], bl[n], acc[m][n], 0, 0, 0);
          acc[m][n] = __builtin_amdgcn_mfma_f32_16x16x32_bf16(al[m][kk], bh[n], acc[m][n], 0, 0, 0);
        }
    }

    // fold |e|^2 - 2*dot, update running best / 2nd-best
#pragma unroll
    for (int n = 0; n < 4; n++) {
      int col = cg * 64 + n * 16 + l15;
#pragma unroll
      for (int m = 0; m < 2; m++)
#pragma unroll
        for (int r = 0; r < 4; r++) {
          float sc = fmaf(-2.0f, acc[m][n][r], e2r[n]);
          if (sc < bv[m][r]) { b2[m][r] = bv[m][r]; bv[m][r] = sc; bi[m][r] = col; }
          else if (sc < b2[m][r]) b2[m][r] = sc;
        }
    }

    __syncthreads();   // drains next-chunk loads + releases buf(cur) for overwrite
    cur ^= 1;
  }

  // reduce over the 16 column-lanes; tie-break smaller index
#pragma unroll
  for (int m = 0; m < 2; m++)
#pragma unroll
    for (int r = 0; r < 4; r++) {
      float v = bv[m][r], v2 = b2[m][r];
      int ii = bi[m][r];
      for (int mask = 1; mask < 16; mask <<= 1) {
        float ov = __shfl_xor(v, mask);
        float o2 = __shfl_xor(v2, mask);
        int   oi = __shfl_xor(ii, mask);
        float hi = fmaxf(v, ov);
        v2 = fminf(fminf(v2, o2), hi);
        if (ov < v || (ov == v && oi < ii)) { v = ov; ii = oi; }
      }
      if (l15 == 0) {
        int row = rbase + w * 32 + m * 16 + lo4 * 4 + r;
        idx_arr[row] = ii;
        out_idx[row] = (float)ii;
        if (v2 - v < 1.5e-3f) { int p = atomicAdd(nflag, 1); flags[p] = row; }
      }
    }
}

// ---- exact f64 recompute for near-tie rows ----
__global__ void fb_k(const float* __restrict__ x, const float* __restrict__ emb,
                     const double* __restrict__ en2d, const int* __restrict__ nflag,
                     const int* __restrict__ flags, int* __restrict__ idx_arr,
                     float* __restrict__ out_idx) {
  int n = *nflag;
  __shared__ double xsh[DIM];
  __shared__ double sv[256];
  __shared__ int    si[256];
  for (int f = blockIdx.x; f < n; f += gridDim.x) {
    int row = flags[f];
    __syncthreads();
    if (threadIdx.x < DIM) xsh[threadIdx.x] = (double)x[row * DIM + threadIdx.x];
    __syncthreads();
    double bvv = 1e300; int bii = 0;
    for (int q = 0; q < 4; q++) {
      int c = threadIdx.x * 4 + q;
      double xe = 0.0;
      for (int d = 0; d < DIM; d++) xe = fma((double)emb[c * DIM + d], xsh[d], xe);
      double s = en2d[c] - 2.0 * xe;
      if (s < bvv || (s == bvv && c < bii)) { bvv = s; bii = c; }
    }
    sv[threadIdx.x] = bvv; si[threadIdx.x] = bii;
    __syncthreads();
    for (int s2 = 128; s2 > 0; s2 >>= 1) {
      if ((int)threadIdx.x < s2) {
        double ov = sv[threadIdx.x + s2]; int oi = si[threadIdx.x + s2];
        if (ov < sv[threadIdx.x] || (ov == sv[threadIdx.x] && oi < si[threadIdx.x])) {
          sv[threadIdx.x] = ov; si[threadIdx.x] = oi;
        }
      }
      __syncthreads();
    }
    if (threadIdx.x == 0) { idx_arr[row] = si[0]; out_idx[row] = (float)si[0]; }
  }
}

// ---- histogram of idx (LDS bins, few global atomics) ----
__global__ void hist_k(const int* __restrict__ idx, unsigned* __restrict__ icounts) {
  __shared__ unsigned bins[NK];
  int t = threadIdx.x;
  for (int b = t; b < NK; b += 256) bins[b] = 0u;
  __syncthreads();
#pragma unroll
  for (int j = 0; j < 4; j++) {
    int r = blockIdx.x * 1024 + j * 256 + t;
    atomicAdd(&bins[idx[r]], 1u);
  }
  __syncthreads();
  for (int b = t; b < NK; b += 256)
    if (bins[b]) atomicAdd(&icounts[b], bins[b]);
}

// ---- exclusive prefix sum -> offsets, cursors ----
__global__ void prefix_k(const unsigned* __restrict__ icounts, unsigned* __restrict__ offsets,
                         unsigned* __restrict__ cursors) {
  __shared__ unsigned sc[NK];
  int t = threadIdx.x;
  unsigned c0 = icounts[t];
  sc[t] = c0;
  __syncthreads();
  for (int off = 1; off < NK; off <<= 1) {
    unsigned v = (t >= off) ? sc[t - off] : 0u;
    __syncthreads();
    sc[t] += v;
    __syncthreads();
  }
  unsigned excl = sc[t] - c0;
  offsets[t] = excl;
  cursors[t] = excl;
}

// ---- scatter row ids into code-sorted order ----
__global__ void scatter_k(const int* __restrict__ idx, unsigned* __restrict__ cursors,
                          int* __restrict__ order) {
  int t = threadIdx.x;
#pragma unroll
  for (int j = 0; j < 4; j++) {
    int r = blockIdx.x * 1024 + j * 256 + t;
    int k = idx[r];
    unsigned p = atomicAdd(&cursors[k], 1u);
    order[p] = r;
  }
}

// ---- fused gather: out_q, loss partials, dw_embed sums (no atomics) ----
__global__ __launch_bounds__(128)
void fgather_k(const float* __restrict__ x, const float* __restrict__ emb,
               const unsigned* __restrict__ offsets, const unsigned* __restrict__ icounts,
               const int* __restrict__ order, float* __restrict__ out_q,
               float* __restrict__ dwsum, float* __restrict__ partial) {
  int k = blockIdx.x, t = threadIdx.x;
  float e = emb[k * DIM + t];
  unsigned s = offsets[k], cnt = icounts[k];
  float acc = 0.f, ls = 0.f;
  for (unsigned j = 0; j < cnt; j++) {
    int row = order[s + j];
    float xv = x[row * DIM + t];
    out_q[row * DIM + t] = e;
    acc += xv;
    float d = e - xv;
    ls += d * d;
  }
  dwsum[k * DIM + t] = acc;
  __shared__ float red[128];
  red[t] = ls;
  __syncthreads();
  for (int sh = 64; sh > 0; sh >>= 1) {
    if (t < sh) red[t] += red[t + sh];
    __syncthreads();
  }
  if (t == 0) partial[k] = red[0];
}

// ---- loss + cluster-size EMA + csk ----
__global__ void fin_k(const float* __restrict__ cluster_size, const unsigned* __restrict__ icounts,
                      const float* __restrict__ partial, float* __restrict__ out_loss,
                      float* __restrict__ out_ncs, float* __restrict__ csk) {
  __shared__ float red[NK];
  int t = threadIdx.x;
  red[t] = partial[t];
  __syncthreads();
  for (int s = 512; s > 0; s >>= 1) {
    if (t < s) red[t] += red[t + s];
    __syncthreads();
  }
  float S = red[0];
  __syncthreads();
  if (t == 0) out_loss[0] = 2.0f * S / 8388608.0f;
  float ncs = cluster_size[t] * 0.99f + 0.01f * (float)icounts[t];
  out_ncs[t] = ncs;
  red[t] = ncs;
  __syncthreads();
  for (int s = 512; s > 0; s >>= 1) {
    if (t < s) red[t] += red[t + s];
    __syncthreads();
  }
  float n = red[0];
  csk[t] = (ncs + 1e-5f) / (n + 1024.0f * 1e-5f) * n;
}

// ---- embed_avg EMA + new embedding ----
__global__ void emb_k(const float* __restrict__ embed_avg, const float* __restrict__ dwsum,
                      const float* __restrict__ csk, float* __restrict__ out_nemb,
                      float* __restrict__ out_nea) {
  int i = blockIdx.x * 256 + threadIdx.x;
  float na = embed_avg[i] * 0.99f + 0.01f * dwsum[i];
  out_nea[i] = na;
  out_nemb[i] = na / csk[i >> 7];
}

extern "C" void kernel_launch(void* const* d_in, const int* in_sizes, int n_in,
                              void* d_out, int out_size, void* d_ws, size_t ws_size,
                              hipStream_t stream) {
  const float* x   = (const float*)d_in[0];
  const float* emb = (const float*)d_in[1];
  const float* cs  = (const float*)d_in[2];
  const float* ea  = (const float*)d_in[3];

  float* out      = (float*)d_out;
  float* out_q    = out;                      // [65536,128]
  float* out_loss = out + 8388608;            // scalar
  float* out_idx  = out + 8388609;            // [65536]
  float* out_nemb = out + 8454145;            // [1024,128]
  float* out_ncs  = out + 8585217;            // [1024]
  float* out_nea  = out + 8586241;            // [1024,128]

  float* W        = (float*)d_ws;
  float* en2      = W;                              // [0,1024)
  char*  bpack    = (char*)(W + 1024);              // 512KB pre-swizzled image
  float* dwsum    = W + 1024;                       // aliases bpack (used after argmin)
  float* csk      = W + 132096;                     // 1024
  float* partial  = W + 133120;                     // 1024
  unsigned* icounts = (unsigned*)(W + 134144);      // 1024
  unsigned* offsets = (unsigned*)(W + 135168);      // 1024
  unsigned* cursors = (unsigned*)(W + 136192);      // 1024
  int*   nflag    = (int*)(W + 137216);             // 1
  int*   flags    = (int*)(W + 137232);             // 65536
  int*   idx_arr  = (int*)(W + 202768);             // 65536
  int*   order    = (int*)(W + 268304);             // 65536
  double* en2d    = (double*)(W + 333840);          // 1024 doubles

  bprep_k<<<64, 256, 0, stream>>>(emb, bpack, nflag, icounts);
  enorm_k<<<4, 256, 0, stream>>>(emb, en2, en2d);
  argmin_k<<<512, 256, 0, stream>>>(x, bpack, en2, idx_arr, out_idx, nflag, flags);
  fb_k<<<1024, 256, 0, stream>>>(x, emb, en2d, nflag, flags, idx_arr, out_idx);
  hist_k<<<64, 256, 0, stream>>>(idx_arr, icounts);
  prefix_k<<<1, 1024, 0, stream>>>(icounts, offsets, cursors);
  scatter_k<<<64, 256, 0, stream>>>(idx_arr, cursors, order);
  fgather_k<<<1024, 128, 0, stream>>>(x, emb, offsets, icounts, order, out_q, dwsum, partial);
  fin_k<<<1, 1024, 0, stream>>>(cs, icounts, partial, out_loss, out_ncs, csk);
  emb_k<<<512, 256, 0, stream>>>(ea, dwsum, csk, out_nemb, out_nea);
}

// Round 5
// 203.039 us; speedup vs baseline: 1.9561x; 1.3386x over previous
//
#include <hip/hip_runtime.h>

typedef __attribute__((ext_vector_type(8))) short short8;
typedef __attribute__((ext_vector_type(4))) float f32x4;

constexpr int NTOK = 65536;
constexpr int DIM  = 128;
constexpr int NK   = 1024;

__device__ __forceinline__ unsigned short f2bf(float f) {
  unsigned int u = __float_as_uint(f);
  unsigned int r = u + 0x7fffu + ((u >> 16) & 1u);
  return (unsigned short)(r >> 16);
}
__device__ __forceinline__ float bf2f(unsigned short h) {
  return __uint_as_float(((unsigned int)h) << 16);
}
__device__ __forceinline__ void gload_lds16(const void* g, void* l) {
  __builtin_amdgcn_global_load_lds(
      (const __attribute__((address_space(1))) unsigned int*)g,
      (__attribute__((address_space(3))) unsigned int*)l, 16, 0, 0);
}

// ---- B prep: emb -> pre-swizzled LDS-image bf16 hi|lo chunks + embT (f32 transpose) ----
__global__ void bprep_k(const float* __restrict__ emb, char* __restrict__ bp,
                        float* __restrict__ embT, int* __restrict__ nflag,
                        unsigned* __restrict__ icounts) {
  int i = blockIdx.x * 256 + threadIdx.x;   // 0..16383
  if (i == 0) *nflag = 0;
  if (i < NK) icounts[i] = 0u;
  int c = i >> 4;          // code 0..1023
  int g = i & 15;          // dim group (8 dims each)
  float4 v0 = *(const float4*)&emb[c * 128 + g * 8];
  float4 v1 = *(const float4*)&emb[c * 128 + g * 8 + 4];
  float vf[8] = {v0.x, v0.y, v0.z, v0.w, v1.x, v1.y, v1.z, v1.w};
  unsigned short hh[8], ll[8];
#pragma unroll
  for (int j = 0; j < 8; j++) {
    hh[j] = f2bf(vf[j]);
    ll[j] = f2bf(vf[j] - bf2f(hh[j]));
    embT[(g * 8 + j) * NK + c] = vf[j];
  }
  uint4 hv, lv;
  hv.x = (unsigned)hh[0] | ((unsigned)hh[1] << 16); hv.y = (unsigned)hh[2] | ((unsigned)hh[3] << 16);
  hv.z = (unsigned)hh[4] | ((unsigned)hh[5] << 16); hv.w = (unsigned)hh[6] | ((unsigned)hh[7] << 16);
  lv.x = (unsigned)ll[0] | ((unsigned)ll[1] << 16); lv.y = (unsigned)ll[2] | ((unsigned)ll[3] << 16);
  lv.z = (unsigned)ll[4] | ((unsigned)ll[5] << 16); lv.w = (unsigned)ll[6] | ((unsigned)ll[7] << 16);
  int cg = c >> 6, cl = c & 63;
  int sw = (cl & 7) << 4;
  char* base = bp + cg * 32768 + cl * 512;
  *(uint4*)(base + ((g * 16) ^ sw)) = hv;
  *(uint4*)(base + 256 + ((g * 16) ^ sw)) = lv;
}

// ---- |e_k|^2 in f64 (exact, for fallback) + f32 (for scores) ----
__global__ void enorm_k(const float* __restrict__ emb, float* __restrict__ en2,
                        double* __restrict__ en2d) {
  int k = blockIdx.x * 256 + threadIdx.x;
  double acc = 0.0;
  for (int d = 0; d < DIM; d += 4) {
    float4 v = *(const float4*)&emb[k * DIM + d];
    acc = fma((double)v.x, (double)v.x, acc);
    acc = fma((double)v.y, (double)v.y, acc);
    acc = fma((double)v.z, (double)v.z, acc);
    acc = fma((double)v.w, (double)v.w, acc);
  }
  en2[k] = (float)acc;
  en2d[k] = acc;
}

// ---- main: MFMA bf16-split distance + running argmin ----
__global__ __launch_bounds__(256, 2)
void argmin_k(const float* __restrict__ x, const char* __restrict__ bp,
              const float* __restrict__ en2, int* __restrict__ idx_arr,
              float* __restrict__ out_idx, int* __restrict__ nflag,
              int* __restrict__ flags) {
  __shared__ __align__(16) char smem[65536];
  const int t    = threadIdx.x;
  const int lane = t & 63;
  const int w    = t >> 6;
  const int l15  = lane & 15;
  const int lo4  = lane >> 4;
  const int rbase = blockIdx.x * 128;

  // stage x -> LDS as bf16 hi|lo, row-major 512B/row, XOR swizzle (one-time)
#pragma unroll
  for (int i = 0; i < 8; i++) {
    int f = i * 2048 + t * 8;
    int row = f >> 7;
    int d = f & 127;
    const float* xp = &x[(rbase + row) * 128 + d];
    float4 v0 = *(const float4*)xp;
    float4 v1 = *(const float4*)(xp + 4);
    float vf[8] = {v0.x, v0.y, v0.z, v0.w, v1.x, v1.y, v1.z, v1.w};
    unsigned short hh[8], ll[8];
#pragma unroll
    for (int j = 0; j < 8; j++) {
      hh[j] = f2bf(vf[j]);
      ll[j] = f2bf(vf[j] - bf2f(hh[j]));
    }
    uint4 hv, lv;
    hv.x = (unsigned)hh[0] | ((unsigned)hh[1] << 16); hv.y = (unsigned)hh[2] | ((unsigned)hh[3] << 16);
    hv.z = (unsigned)hh[4] | ((unsigned)hh[5] << 16); hv.w = (unsigned)hh[6] | ((unsigned)hh[7] << 16);
    lv.x = (unsigned)ll[0] | ((unsigned)ll[1] << 16); lv.y = (unsigned)ll[2] | ((unsigned)ll[3] << 16);
    lv.z = (unsigned)ll[4] | ((unsigned)ll[5] << 16); lv.w = (unsigned)ll[6] | ((unsigned)ll[7] << 16);
    int sw = (row & 7) << 4;
    int byteH = row * 512 + d * 2;
    *(uint4*)&smem[byteH ^ sw] = hv;
    *(uint4*)&smem[(byteH + 256) ^ sw] = lv;
  }
  __syncthreads();

  short8 ah[2][4], al[2][4];
#pragma unroll
  for (int m = 0; m < 2; m++)
#pragma unroll
    for (int kk = 0; kk < 4; kk++) {
      int row = w * 32 + m * 16 + l15;
      int sw = (row & 7) << 4;
      int byte_ = row * 512 + kk * 64 + (lo4 << 4);
      ah[m][kk] = *(short8*)&smem[byte_ ^ sw];
      al[m][kk] = *(short8*)&smem[(byte_ + 256) ^ sw];
    }
  __syncthreads();

  float bv[2][4], b2[2][4];
  int bi[2][4];
#pragma unroll
  for (int m = 0; m < 2; m++)
#pragma unroll
    for (int r = 0; r < 4; r++) { bv[m][r] = 3.0e38f; b2[m][r] = 3.0e38f; bi[m][r] = 0; }

  {
    const char* gsrc = bp + w * 8192 + lane * 16;
    char* ldst = smem + w * 8192;
#pragma unroll
    for (int u = 0; u < 8; u++) gload_lds16(gsrc + u * 1024, ldst + u * 1024);
  }
  __syncthreads();

  int cur = 0;
  for (int cg = 0; cg < 16; cg++) {
    if (cg < 15) {
      const char* gsrc = bp + (cg + 1) * 32768 + w * 8192 + lane * 16;
      char* ldst = smem + (cur ^ 1) * 32768 + w * 8192;
#pragma unroll
      for (int u = 0; u < 8; u++) gload_lds16(gsrc + u * 1024, ldst + u * 1024);
    }

    float e2r[4];
#pragma unroll
    for (int n = 0; n < 4; n++) e2r[n] = en2[cg * 64 + n * 16 + l15];

    f32x4 acc[2][4];
#pragma unroll
    for (int m = 0; m < 2; m++)
#pragma unroll
      for (int n = 0; n < 4; n++) acc[m][n] = (f32x4)(0.0f);

    const int bufb = cur * 32768;
#pragma unroll
    for (int kk = 0; kk < 4; kk++) {
      short8 bh[4], bl[4];
#pragma unroll
      for (int n = 0; n < 4; n++) {
        int code_l = n * 16 + l15;
        int sw = (code_l & 7) << 4;
        int byte_ = code_l * 512 + kk * 64 + (lo4 << 4);
        bh[n] = *(short8*)&smem[bufb + (byte_ ^ sw)];
        bl[n] = *(short8*)&smem[bufb + ((byte_ + 256) ^ sw)];
      }
#pragma unroll
      for (int m = 0; m < 2; m++)
#pragma unroll
        for (int n = 0; n < 4; n++) {
          acc[m][n] = __builtin_amdgcn_mfma_f32_16x16x32_bf16(ah[m][kk], bh[n], acc[m][n], 0, 0, 0);
          acc[m][n] = __builtin_amdgcn_mfma_f32_16x16x32_bf16(ah[m][kk], bl[n], acc[m][n], 0, 0, 0);
          acc[m][n] = __builtin_amdgcn_mfma_f32_16x16x32_bf16(al[m][kk], bh[n], acc[m][n], 0, 0, 0);
        }
    }

#pragma unroll
    for (int n = 0; n < 4; n++) {
      int col = cg * 64 + n * 16 + l15;
#pragma unroll
      for (int m = 0; m < 2; m++)
#pragma unroll
        for (int r = 0; r < 4; r++) {
          float sc = fmaf(-2.0f, acc[m][n][r], e2r[n]);
          if (sc < bv[m][r]) { b2[m][r] = bv[m][r]; bv[m][r] = sc; bi[m][r] = col; }
          else if (sc < b2[m][r]) b2[m][r] = sc;
        }
    }

    __syncthreads();
    cur ^= 1;
  }

#pragma unroll
  for (int m = 0; m < 2; m++)
#pragma unroll
    for (int r = 0; r < 4; r++) {
      float v = bv[m][r], v2 = b2[m][r];
      int ii = bi[m][r];
      for (int mask = 1; mask < 16; mask <<= 1) {
        float ov = __shfl_xor(v, mask);
        float o2 = __shfl_xor(v2, mask);
        int   oi = __shfl_xor(ii, mask);
        float hi = fmaxf(v, ov);
        v2 = fminf(fminf(v2, o2), hi);
        if (ov < v || (ov == v && oi < ii)) { v = ov; ii = oi; }
      }
      if (l15 == 0) {
        int row = rbase + w * 32 + m * 16 + lo4 * 4 + r;
        idx_arr[row] = ii;
        out_idx[row] = (float)ii;
        if (v2 - v < 1.5e-3f) { int p = atomicAdd(nflag, 1); flags[p] = row; }
      }
    }
}

// ---- exact f64 recompute for near-tie rows (coalesced via embT) ----
__global__ __launch_bounds__(256)
void fb_k(const float* __restrict__ x, const float* __restrict__ embT,
          const double* __restrict__ en2d, const int* __restrict__ nflag,
          const int* __restrict__ flags, int* __restrict__ idx_arr,
          float* __restrict__ out_idx) {
  int n = *nflag;
  __shared__ double xsh[DIM];
  __shared__ double sv[256];
  __shared__ int    si[256];
  int t = threadIdx.x;
  for (int f = blockIdx.x; f < n; f += gridDim.x) {
    int row = flags[f];
    __syncthreads();
    if (t < DIM) xsh[t] = (double)x[row * DIM + t];
    __syncthreads();
    double xe0 = 0.0, xe1 = 0.0, xe2 = 0.0, xe3 = 0.0;
#pragma unroll 4
    for (int d = 0; d < DIM; d++) {
      float4 v = *(const float4*)&embT[d * NK + t * 4];
      double xd = xsh[d];
      xe0 = fma((double)v.x, xd, xe0);
      xe1 = fma((double)v.y, xd, xe1);
      xe2 = fma((double)v.z, xd, xe2);
      xe3 = fma((double)v.w, xd, xe3);
    }
    double s0 = en2d[t * 4 + 0] - 2.0 * xe0;
    double s1 = en2d[t * 4 + 1] - 2.0 * xe1;
    double s2 = en2d[t * 4 + 2] - 2.0 * xe2;
    double s3 = en2d[t * 4 + 3] - 2.0 * xe3;
    double bvv = s0; int bii = t * 4;
    if (s1 < bvv) { bvv = s1; bii = t * 4 + 1; }
    if (s2 < bvv) { bvv = s2; bii = t * 4 + 2; }
    if (s3 < bvv) { bvv = s3; bii = t * 4 + 3; }
    sv[t] = bvv; si[t] = bii;
    __syncthreads();
    for (int sh = 128; sh > 0; sh >>= 1) {
      if (t < sh) {
        double ov = sv[t + sh]; int oi = si[t + sh];
        if (ov < sv[t] || (ov == sv[t] && oi < si[t])) { sv[t] = ov; si[t] = oi; }
      }
      __syncthreads();
    }
    if (t == 0) { idx_arr[row] = si[0]; out_idx[row] = (float)si[0]; }
  }
}

// ---- histogram of idx (LDS bins, few global atomics) ----
__global__ void hist_k(const int* __restrict__ idx, unsigned* __restrict__ icounts) {
  __shared__ unsigned bins[NK];
  int t = threadIdx.x;
  for (int b = t; b < NK; b += 256) bins[b] = 0u;
  __syncthreads();
#pragma unroll
  for (int j = 0; j < 4; j++) {
    int r = blockIdx.x * 1024 + j * 256 + t;
    atomicAdd(&bins[idx[r]], 1u);
  }
  __syncthreads();
  for (int b = t; b < NK; b += 256)
    if (bins[b]) atomicAdd(&icounts[b], bins[b]);
}

// ---- exclusive prefix sum -> offsets, cursors ----
__global__ void prefix_k(const unsigned* __restrict__ icounts, unsigned* __restrict__ offsets,
                         unsigned* __restrict__ cursors) {
  __shared__ unsigned sc[NK];
  int t = threadIdx.x;
  unsigned c0 = icounts[t];
  sc[t] = c0;
  __syncthreads();
  for (int off = 1; off < NK; off <<= 1) {
    unsigned v = (t >= off) ? sc[t - off] : 0u;
    __syncthreads();
    sc[t] += v;
    __syncthreads();
  }
  unsigned excl = sc[t] - c0;
  offsets[t] = excl;
  cursors[t] = excl;
}

// ---- scatter row ids into code-sorted order ----
__global__ void scatter_k(const int* __restrict__ idx, unsigned* __restrict__ cursors,
                          int* __restrict__ order) {
  int t = threadIdx.x;
#pragma unroll
  for (int j = 0; j < 4; j++) {
    int r = blockIdx.x * 1024 + j * 256 + t;
    int k = idx[r];
    unsigned p = atomicAdd(&cursors[k], 1u);
    order[p] = r;
  }
}

// ---- fused gather: out_q, loss partials, dw_embed sums (no atomics; 2 rows/iter) ----
__global__ __launch_bounds__(256)
void fgather_k(const float* __restrict__ x, const float* __restrict__ emb,
               const unsigned* __restrict__ offsets, const unsigned* __restrict__ icounts,
               const int* __restrict__ order, float* __restrict__ out_q,
               float* __restrict__ dwsum, float* __restrict__ partial) {
  int k = blockIdx.x, t = threadIdx.x;
  int d = t & 127, h = t >> 7;
  float e = emb[k * DIM + d];
  unsigned s = offsets[k], cnt = icounts[k];
  float acc = 0.f, ls = 0.f;
  for (unsigned j = h; j < cnt; j += 2) {
    int row = order[s + j];
    float xv = x[row * DIM + d];
    out_q[row * DIM + d] = e;
    acc += xv;
    float dd = e - xv;
    ls += dd * dd;
  }
  __shared__ float sa[256], sl[256];
  sa[t] = acc; sl[t] = ls;
  __syncthreads();
  if (t < 128) dwsum[k * DIM + t] = sa[t] + sa[t + 128];
  for (int sh = 128; sh > 0; sh >>= 1) {
    if (t < sh) sl[t] += sl[t + sh];
    __syncthreads();
  }
  if (t == 0) partial[k] = sl[0];
}

// ---- loss + cluster-size EMA + csk ----
__global__ void fin_k(const float* __restrict__ cluster_size, const unsigned* __restrict__ icounts,
                      const float* __restrict__ partial, float* __restrict__ out_loss,
                      float* __restrict__ out_ncs, float* __restrict__ csk) {
  __shared__ float red[NK];
  int t = threadIdx.x;
  red[t] = partial[t];
  __syncthreads();
  for (int s = 512; s > 0; s >>= 1) {
    if (t < s) red[t] += red[t + s];
    __syncthreads();
  }
  float S = red[0];
  __syncthreads();
  if (t == 0) out_loss[0] = 2.0f * S / 8388608.0f;
  float ncs = cluster_size[t] * 0.99f + 0.01f * (float)icounts[t];
  out_ncs[t] = ncs;
  red[t] = ncs;
  __syncthreads();
  for (int s = 512; s > 0; s >>= 1) {
    if (t < s) red[t] += red[t + s];
    __syncthreads();
  }
  float n = red[0];
  csk[t] = (ncs + 1e-5f) / (n + 1024.0f * 1e-5f) * n;
}

// ---- embed_avg EMA + new embedding ----
__global__ void emb_k(const float* __restrict__ embed_avg, const float* __restrict__ dwsum,
                      const float* __restrict__ csk, float* __restrict__ out_nemb,
                      float* __restrict__ out_nea) {
  int i = blockIdx.x * 256 + threadIdx.x;
  float na = embed_avg[i] * 0.99f + 0.01f * dwsum[i];
  out_nea[i] = na;
  out_nemb[i] = na / csk[i >> 7];
}

extern "C" void kernel_launch(void* const* d_in, const int* in_sizes, int n_in,
                              void* d_out, int out_size, void* d_ws, size_t ws_size,
                              hipStream_t stream) {
  const float* x   = (const float*)d_in[0];
  const float* emb = (const float*)d_in[1];
  const float* cs  = (const float*)d_in[2];
  const float* ea  = (const float*)d_in[3];

  float* out      = (float*)d_out;
  float* out_q    = out;                      // [65536,128]
  float* out_loss = out + 8388608;            // scalar
  float* out_idx  = out + 8388609;            // [65536]
  float* out_nemb = out + 8454145;            // [1024,128]
  float* out_ncs  = out + 8585217;            // [1024]
  float* out_nea  = out + 8586241;            // [1024,128]

  float* W        = (float*)d_ws;
  float* en2      = W;                              // [0,1024)
  char*  bpack    = (char*)(W + 1024);              // 512KB pre-swizzled image
  float* dwsum    = W + 1024;                       // aliases bpack (used after argmin)
  float* csk      = W + 132096;                     // 1024
  float* partial  = W + 133120;                     // 1024
  unsigned* icounts = (unsigned*)(W + 134144);      // 1024
  unsigned* offsets = (unsigned*)(W + 135168);      // 1024
  unsigned* cursors = (unsigned*)(W + 136192);      // 1024
  int*   nflag    = (int*)(W + 137216);             // 1
  int*   flags    = (int*)(W + 137232);             // 65536
  int*   idx_arr  = (int*)(W + 202768);             // 65536
  int*   order    = (int*)(W + 268304);             // 65536
  double* en2d    = (double*)(W + 333840);          // 1024 doubles -> ends 335888
  float* embT     = W + 335888;                     // 131072 floats (512KB transpose)

  bprep_k<<<64, 256, 0, stream>>>(emb, bpack, embT, nflag, icounts);
  enorm_k<<<4, 256, 0, stream>>>(emb, en2, en2d);
  argmin_k<<<512, 256, 0, stream>>>(x, bpack, en2, idx_arr, out_idx, nflag, flags);
  fb_k<<<1024, 256, 0, stream>>>(x, embT, en2d, nflag, flags, idx_arr, out_idx);
  hist_k<<<64, 256, 0, stream>>>(idx_arr, icounts);
  prefix_k<<<1, 1024, 0, stream>>>(icounts, offsets, cursors);
  scatter_k<<<64, 256, 0, stream>>>(idx_arr, cursors, order);
  fgather_k<<<1024, 256, 0, stream>>>(x, emb, offsets, icounts, order, out_q, dwsum, partial);
  fin_k<<<1, 1024, 0, stream>>>(cs, icounts, partial, out_loss, out_ncs, csk);
  emb_k<<<512, 256, 0, stream>>>(ea, dwsum, csk, out_nemb, out_nea);
}

// Round 6
// 189.087 us; speedup vs baseline: 2.1005x; 1.0738x over previous
//
#include <hip/hip_runtime.h>

typedef __attribute__((ext_vector_type(8))) short short8;
typedef __attribute__((ext_vector_type(4))) float f32x4;

constexpr int NTOK = 65536;
constexpr int DIM  = 128;
constexpr int NK   = 1024;

__device__ __forceinline__ unsigned short f2bf(float f) {
  unsigned int u = __float_as_uint(f);
  unsigned int r = u + 0x7fffu + ((u >> 16) & 1u);
  return (unsigned short)(r >> 16);
}
__device__ __forceinline__ float bf2f(unsigned short h) {
  return __uint_as_float(((unsigned int)h) << 16);
}
__device__ __forceinline__ void gload_lds16(const void* g, void* l) {
  __builtin_amdgcn_global_load_lds(
      (const __attribute__((address_space(1))) unsigned int*)g,
      (__attribute__((address_space(3))) unsigned int*)l, 16, 0, 0);
}

// ---- prep: emb -> pre-swizzled bf16 hi|lo chunk image (32 codes/chunk) + embT +
//      f64 |e|^2 + scaled-key e2s; zeroes nflag. (enorm fused via shfl reduce) ----
__global__ void bprep_k(const float* __restrict__ emb, char* __restrict__ bp,
                        float* __restrict__ embT, float* __restrict__ e2s,
                        double* __restrict__ en2d, int* __restrict__ nflag) {
  int i = blockIdx.x * 256 + threadIdx.x;   // 0..16383
  if (i == 0) *nflag = 0;
  int c = i >> 4;          // code
  int g = i & 15;          // dim group (8 dims)
  float4 v0 = *(const float4*)&emb[c * 128 + g * 8];
  float4 v1 = *(const float4*)&emb[c * 128 + g * 8 + 4];
  float vf[8] = {v0.x, v0.y, v0.z, v0.w, v1.x, v1.y, v1.z, v1.w};
  unsigned short hh[8], ll[8];
  double pacc = 0.0;
#pragma unroll
  for (int j = 0; j < 8; j++) {
    hh[j] = f2bf(vf[j]);
    ll[j] = f2bf(vf[j] - bf2f(hh[j]));
    embT[(g * 8 + j) * NK + c] = vf[j];
    pacc = fma((double)vf[j], (double)vf[j], pacc);
  }
  uint4 hv, lv;
  hv.x = (unsigned)hh[0] | ((unsigned)hh[1] << 16); hv.y = (unsigned)hh[2] | ((unsigned)hh[3] << 16);
  hv.z = (unsigned)hh[4] | ((unsigned)hh[5] << 16); hv.w = (unsigned)hh[6] | ((unsigned)hh[7] << 16);
  lv.x = (unsigned)ll[0] | ((unsigned)ll[1] << 16); lv.y = (unsigned)ll[2] | ((unsigned)ll[3] << 16);
  lv.z = (unsigned)ll[4] | ((unsigned)ll[5] << 16); lv.w = (unsigned)ll[6] | ((unsigned)ll[7] << 16);
  int cg = c >> 5, cl = c & 31;
  int sw = (cl & 7) << 4;
  char* base = bp + cg * 16384 + cl * 512;
  *(uint4*)(base + ((g * 16) ^ sw)) = hv;
  *(uint4*)(base + 256 + ((g * 16) ^ sw)) = lv;
#pragma unroll
  for (int mask = 1; mask < 16; mask <<= 1) pacc += __shfl_xor(pacc, mask);
  if (g == 0) {
    en2d[c] = pacc;
    e2s[c] = (float)(pacc * 134217728.0 + 1073741824.0);  // e2*2^27 + 2^30
  }
}

// ---- main: MFMA bf16-split distance + u32-key argmin ----
__global__ __launch_bounds__(256, 4)
void argmin_k(const float* __restrict__ x, const char* __restrict__ bp,
              const float* __restrict__ e2s, int* __restrict__ idx_arr,
              float* __restrict__ out_idx, int* __restrict__ nflag,
              int* __restrict__ flags) {
  __shared__ __align__(16) char smem[32768];
  const int t    = threadIdx.x;
  const int lane = t & 63;
  const int w    = t >> 6;
  const int l15  = lane & 15;
  const int lo4  = lane >> 4;
  const int rbase = blockIdx.x * 128;

  // stage chunk 0 into buf0 (per-wave 4KB, linear)
  {
    const char* gsrc = bp + w * 4096 + lane * 16;
    char* ldst = smem + w * 4096;
#pragma unroll
    for (int u = 0; u < 4; u++) gload_lds16(gsrc + u * 1024, ldst + u * 1024);
  }

  // A-frags: global -> regs with in-reg bf16 hi/lo split (overlaps chunk-0 loads)
  short8 ah[2][4], al[2][4];
#pragma unroll
  for (int m = 0; m < 2; m++)
#pragma unroll
    for (int kk = 0; kk < 4; kk++) {
      const float* xp = &x[(rbase + w * 32 + m * 16 + l15) * 128 + kk * 32 + lo4 * 8];
      float4 v0 = *(const float4*)xp;
      float4 v1 = *(const float4*)(xp + 4);
      float vf[8] = {v0.x, v0.y, v0.z, v0.w, v1.x, v1.y, v1.z, v1.w};
      unsigned short hh[8], ll[8];
#pragma unroll
      for (int j = 0; j < 8; j++) {
        hh[j] = f2bf(vf[j]);
        ll[j] = f2bf(vf[j] - bf2f(hh[j]));
      }
      unsigned hu[4] = {(unsigned)hh[0] | ((unsigned)hh[1] << 16), (unsigned)hh[2] | ((unsigned)hh[3] << 16),
                        (unsigned)hh[4] | ((unsigned)hh[5] << 16), (unsigned)hh[6] | ((unsigned)hh[7] << 16)};
      unsigned lu[4] = {(unsigned)ll[0] | ((unsigned)ll[1] << 16), (unsigned)ll[2] | ((unsigned)ll[3] << 16),
                        (unsigned)ll[4] | ((unsigned)ll[5] << 16), (unsigned)ll[6] | ((unsigned)ll[7] << 16)};
      ah[m][kk] = *(short8*)hu;
      al[m][kk] = *(short8*)lu;
    }

  unsigned bv[2][4], b2[2][4];
#pragma unroll
  for (int m = 0; m < 2; m++)
#pragma unroll
    for (int r = 0; r < 4; r++) { bv[m][r] = 0xFFFFFFFFu; b2[m][r] = 0xFFFFFFFFu; }

  __syncthreads();   // chunk 0 resident

  int cur = 0;
  for (int cg = 0; cg < 32; cg++) {
    if (cg < 31) {
      const char* gsrc = bp + (cg + 1) * 16384 + w * 4096 + lane * 16;
      char* ldst = smem + (cur ^ 1) * 16384 + w * 4096;
#pragma unroll
      for (int u = 0; u < 4; u++) gload_lds16(gsrc + u * 1024, ldst + u * 1024);
    }

    float e2a = e2s[cg * 32 + l15];
    float e2b = e2s[cg * 32 + 16 + l15];

    f32x4 acc[2][2];
#pragma unroll
    for (int m = 0; m < 2; m++)
#pragma unroll
      for (int n = 0; n < 2; n++) acc[m][n] = (f32x4)(0.0f);

    const int bufb = cur * 16384;
#pragma unroll
    for (int kk = 0; kk < 4; kk++) {
      short8 bh[2], bl[2];
#pragma unroll
      for (int n = 0; n < 2; n++) {
        int code_l = n * 16 + l15;
        int sw = (code_l & 7) << 4;
        int byte_ = code_l * 512 + kk * 64 + (lo4 << 4);
        bh[n] = *(short8*)&smem[bufb + (byte_ ^ sw)];
        bl[n] = *(short8*)&smem[bufb + ((byte_ + 256) ^ sw)];
      }
#pragma unroll
      for (int m = 0; m < 2; m++)
#pragma unroll
        for (int n = 0; n < 2; n++) {
          acc[m][n] = __builtin_amdgcn_mfma_f32_16x16x32_bf16(ah[m][kk], bh[n], acc[m][n], 0, 0, 0);
          acc[m][n] = __builtin_amdgcn_mfma_f32_16x16x32_bf16(ah[m][kk], bl[n], acc[m][n], 0, 0, 0);
          acc[m][n] = __builtin_amdgcn_mfma_f32_16x16x32_bf16(al[m][kk], bh[n], acc[m][n], 0, 0, 0);
        }
    }

    // u32-key epilogue: key = (u32(e2s - 2^28*dot) & ~1023) | col
#pragma unroll
    for (int n = 0; n < 2; n++) {
      unsigned col = (unsigned)(cg * 32 + n * 16 + l15);
      float e2v = n ? e2b : e2a;
#pragma unroll
      for (int m = 0; m < 2; m++)
#pragma unroll
        for (int r = 0; r < 4; r++) {
          float ks = fmaf(acc[m][n][r], -268435456.0f, e2v);
          unsigned key = ((unsigned)ks & 0xFFFFFC00u) | col;
          unsigned old = bv[m][r];
          bv[m][r] = min(old, key);
          b2[m][r] = min(b2[m][r], max(old, key));
        }
    }

    __syncthreads();
    cur ^= 1;
  }

#pragma unroll
  for (int m = 0; m < 2; m++)
#pragma unroll
    for (int r = 0; r < 4; r++) {
      unsigned v = bv[m][r], v2 = b2[m][r];
      for (int mask = 1; mask < 16; mask <<= 1) {
        unsigned ov = __shfl_xor(v, mask);
        unsigned o2 = __shfl_xor(v2, mask);
        v2 = min(min(v2, o2), max(v, ov));
        v  = min(v, ov);
      }
      if (l15 == 0) {
        int row = rbase + w * 32 + m * 16 + lo4 * 4 + r;
        int ii = (int)(v & 1023u);
        idx_arr[row] = ii;
        out_idx[row] = (float)ii;
        if ((v2 >> 10) - (v >> 10) < 197u) {   // gap < 1.5e-3 in score units
          int p = atomicAdd(nflag, 1); flags[p] = row;
        }
      }
    }
}

// ---- exact f64 recompute for near-tie rows (coalesced via embT) ----
__global__ __launch_bounds__(256)
void fb_k(const float* __restrict__ x, const float* __restrict__ embT,
          const double* __restrict__ en2d, const int* __restrict__ nflag,
          const int* __restrict__ flags, int* __restrict__ idx_arr,
          float* __restrict__ out_idx) {
  int n = *nflag;
  __shared__ double xsh[DIM];
  __shared__ double sv[256];
  __shared__ int    si[256];
  int t = threadIdx.x;
  for (int f = blockIdx.x; f < n; f += gridDim.x) {
    int row = flags[f];
    __syncthreads();
    if (t < DIM) xsh[t] = (double)x[row * DIM + t];
    __syncthreads();
    double xe0 = 0.0, xe1 = 0.0, xe2 = 0.0, xe3 = 0.0;
#pragma unroll 4
    for (int d = 0; d < DIM; d++) {
      float4 v = *(const float4*)&embT[d * NK + t * 4];
      double xd = xsh[d];
      xe0 = fma((double)v.x, xd, xe0);
      xe1 = fma((double)v.y, xd, xe1);
      xe2 = fma((double)v.z, xd, xe2);
      xe3 = fma((double)v.w, xd, xe3);
    }
    double s0 = en2d[t * 4 + 0] - 2.0 * xe0;
    double s1 = en2d[t * 4 + 1] - 2.0 * xe1;
    double s2 = en2d[t * 4 + 2] - 2.0 * xe2;
    double s3 = en2d[t * 4 + 3] - 2.0 * xe3;
    double bvv = s0; int bii = t * 4;
    if (s1 < bvv) { bvv = s1; bii = t * 4 + 1; }
    if (s2 < bvv) { bvv = s2; bii = t * 4 + 2; }
    if (s3 < bvv) { bvv = s3; bii = t * 4 + 3; }
    sv[t] = bvv; si[t] = bii;
    __syncthreads();
    for (int sh = 128; sh > 0; sh >>= 1) {
      if (t < sh) {
        double ov = sv[t + sh]; int oi = si[t + sh];
        if (ov < sv[t] || (ov == sv[t] && oi < si[t])) { sv[t] = ov; si[t] = oi; }
      }
      __syncthreads();
    }
    if (t == 0) { idx_arr[row] = si[0]; out_idx[row] = (float)si[0]; }
  }
}

// ---- per-block histogram (LDS bins, plain stores — no global atomics) ----
__global__ void histb_k(const int* __restrict__ idx, unsigned* __restrict__ bcount) {
  __shared__ unsigned bins[NK];
  int t = threadIdx.x;
  for (int b = t; b < NK; b += 256) bins[b] = 0u;
  __syncthreads();
#pragma unroll
  for (int j = 0; j < 4; j++)
    atomicAdd(&bins[idx[blockIdx.x * 1024 + j * 256 + t]], 1u);
  __syncthreads();
  for (int b = t; b < NK; b += 256) bcount[blockIdx.x * NK + b] = bins[b];
}

// ---- totals + exclusive scan + per-block start cursors (atomic-free) ----
__global__ void scan_k(unsigned* __restrict__ bcount, unsigned* __restrict__ icounts,
                       unsigned* __restrict__ offsets) {
  __shared__ unsigned sc[NK];
  int t = threadIdx.x;
  unsigned tot = 0;
  for (int b = 0; b < 64; b++) tot += bcount[b * NK + t];
  icounts[t] = tot;
  sc[t] = tot;
  __syncthreads();
  for (int off = 1; off < NK; off <<= 1) {
    unsigned v = (t >= off) ? sc[t - off] : 0u;
    __syncthreads();
    sc[t] += v;
    __syncthreads();
  }
  unsigned excl = sc[t] - tot;
  offsets[t] = excl;
  unsigned run = excl;
  for (int b = 0; b < 64; b++) {
    unsigned c = bcount[b * NK + t];
    bcount[b * NK + t] = run;          // becomes per-block start
    run += c;
  }
}

// ---- scatter row ids (LDS cursors; no global atomics) ----
__global__ void scatter_k(const int* __restrict__ idx, const unsigned* __restrict__ bstart,
                          int* __restrict__ order) {
  __shared__ unsigned cur[NK];
  int t = threadIdx.x;
  for (int b = t; b < NK; b += 256) cur[b] = bstart[blockIdx.x * NK + b];
  __syncthreads();
#pragma unroll
  for (int j = 0; j < 4; j++) {
    int r = blockIdx.x * 1024 + j * 256 + t;
    unsigned p = atomicAdd(&cur[idx[r]], 1u);
    order[p] = r;
  }
}

// ---- fused gather: out_q, loss partials, dw_embed sums (no atomics) ----
__global__ __launch_bounds__(256)
void fgather_k(const float* __restrict__ x, const float* __restrict__ emb,
               const unsigned* __restrict__ offsets, const unsigned* __restrict__ icounts,
               const int* __restrict__ order, float* __restrict__ out_q,
               float* __restrict__ dwsum, float* __restrict__ partial) {
  int k = blockIdx.x, t = threadIdx.x;
  int d = t & 127, h = t >> 7;
  float e = emb[k * DIM + d];
  unsigned s = offsets[k], cnt = icounts[k];
  float acc = 0.f, ls = 0.f;
  for (unsigned j = h; j < cnt; j += 2) {
    int row = order[s + j];
    float xv = x[row * DIM + d];
    out_q[row * DIM + d] = e;
    acc += xv;
    float dd = e - xv;
    ls += dd * dd;
  }
  __shared__ float sa[256], sl[256];
  sa[t] = acc; sl[t] = ls;
  __syncthreads();
  if (t < 128) dwsum[k * DIM + t] = sa[t] + sa[t + 128];
  for (int sh = 128; sh > 0; sh >>= 1) {
    if (t < sh) sl[t] += sl[t + sh];
    __syncthreads();
  }
  if (t == 0) partial[k] = sl[0];
}

// ---- loss + cluster-size EMA + csk ----
__global__ void fin_k(const float* __restrict__ cluster_size, const unsigned* __restrict__ icounts,
                      const float* __restrict__ partial, float* __restrict__ out_loss,
                      float* __restrict__ out_ncs, float* __restrict__ csk) {
  __shared__ float red[NK];
  int t = threadIdx.x;
  red[t] = partial[t];
  __syncthreads();
  for (int s = 512; s > 0; s >>= 1) {
    if (t < s) red[t] += red[t + s];
    __syncthreads();
  }
  float S = red[0];
  __syncthreads();
  if (t == 0) out_loss[0] = 2.0f * S / 8388608.0f;
  float ncs = cluster_size[t] * 0.99f + 0.01f * (float)icounts[t];
  out_ncs[t] = ncs;
  red[t] = ncs;
  __syncthreads();
  for (int s = 512; s > 0; s >>= 1) {
    if (t < s) red[t] += red[t + s];
    __syncthreads();
  }
  float n = red[0];
  csk[t] = (ncs + 1e-5f) / (n + 1024.0f * 1e-5f) * n;
}

// ---- embed_avg EMA + new embedding ----
__global__ void emb_k(const float* __restrict__ embed_avg, const float* __restrict__ dwsum,
                      const float* __restrict__ csk, float* __restrict__ out_nemb,
                      float* __restrict__ out_nea) {
  int i = blockIdx.x * 256 + threadIdx.x;
  float na = embed_avg[i] * 0.99f + 0.01f * dwsum[i];
  out_nea[i] = na;
  out_nemb[i] = na / csk[i >> 7];
}

extern "C" void kernel_launch(void* const* d_in, const int* in_sizes, int n_in,
                              void* d_out, int out_size, void* d_ws, size_t ws_size,
                              hipStream_t stream) {
  const float* x   = (const float*)d_in[0];
  const float* emb = (const float*)d_in[1];
  const float* cs  = (const float*)d_in[2];
  const float* ea  = (const float*)d_in[3];

  float* out      = (float*)d_out;
  float* out_q    = out;                      // [65536,128]
  float* out_loss = out + 8388608;            // scalar
  float* out_idx  = out + 8388609;            // [65536]
  float* out_nemb = out + 8454145;            // [1024,128]
  float* out_ncs  = out + 8585217;            // [1024]
  float* out_nea  = out + 8586241;            // [1024,128]

  float* W        = (float*)d_ws;
  float* e2s      = W;                              // [0,1024)
  double* en2d    = (double*)(W + 1024);            // [1024,3072)
  char*  bpack    = (char*)(W + 3072);              // [3072,134144) 512KB image
  float* dwsum    = W + 3072;                       // aliases bpack (dead after argmin)
  float* embT     = W + 134144;                     // [134144,265216) (dead after fb)
  unsigned* bcount = (unsigned*)(W + 134144);       // aliases embT lower: 64x1024
  int*   order    = (int*)(W + 199680);             // aliases embT upper: 65536
  float* partial  = W + 265216;                     // 1024
  unsigned* icounts = (unsigned*)(W + 266240);      // 1024
  unsigned* offsets = (unsigned*)(W + 267264);      // 1024
  float* csk      = W + 268288;                     // 1024
  int*   nflag    = (int*)(W + 269312);             // 1 (+pad)
  int*   flags    = (int*)(W + 269328);             // 65536
  int*   idx_arr  = (int*)(W + 334864);             // 65536

  bprep_k<<<64, 256, 0, stream>>>(emb, bpack, embT, e2s, en2d, nflag);
  argmin_k<<<512, 256, 0, stream>>>(x, bpack, e2s, idx_arr, out_idx, nflag, flags);
  fb_k<<<1024, 256, 0, stream>>>(x, embT, en2d, nflag, flags, idx_arr, out_idx);
  histb_k<<<64, 256, 0, stream>>>(idx_arr, bcount);
  scan_k<<<1, 1024, 0, stream>>>(bcount, icounts, offsets);
  scatter_k<<<64, 256, 0, stream>>>(idx_arr, bcount, order);
  fgather_k<<<1024, 256, 0, stream>>>(x, emb, offsets, icounts, order, out_q, dwsum, partial);
  fin_k<<<1, 1024, 0, stream>>>(cs, icounts, partial, out_loss, out_ncs, csk);
  emb_k<<<512, 256, 0, stream>>>(ea, dwsum, csk, out_nemb, out_nea);
}

// Round 7
// 140.239 us; speedup vs baseline: 2.8321x; 1.3483x over previous
//
#include <hip/hip_runtime.h>

typedef __attribute__((ext_vector_type(8))) short short8;
typedef __attribute__((ext_vector_type(4))) float f32x4;

constexpr int NTOK = 65536;
constexpr int DIM  = 128;
constexpr int NK   = 1024;

__device__ __forceinline__ unsigned short f2bf(float f) {
  unsigned int u = __float_as_uint(f);
  unsigned int r = u + 0x7fffu + ((u >> 16) & 1u);
  return (unsigned short)(r >> 16);
}
__device__ __forceinline__ float bf2f(unsigned short h) {
  return __uint_as_float(((unsigned int)h) << 16);
}
__device__ __forceinline__ void gload_lds16(const void* g, void* l) {
  __builtin_amdgcn_global_load_lds(
      (const __attribute__((address_space(1))) unsigned int*)g,
      (__attribute__((address_space(3))) unsigned int*)l, 16, 0, 0);
}

// ---- prep: emb -> pre-swizzled bf16 hi|lo chunk image (32 codes/chunk) + embT +
//      f64 |e|^2 + scaled-key e2s; zeroes nflag ----
__global__ void bprep_k(const float* __restrict__ emb, char* __restrict__ bp,
                        float* __restrict__ embT, float* __restrict__ e2s,
                        double* __restrict__ en2d, int* __restrict__ nflag) {
  int i = blockIdx.x * 256 + threadIdx.x;   // 0..16383
  if (i == 0) *nflag = 0;
  int c = i >> 4;          // code
  int g = i & 15;          // dim group (8 dims)
  float4 v0 = *(const float4*)&emb[c * 128 + g * 8];
  float4 v1 = *(const float4*)&emb[c * 128 + g * 8 + 4];
  float vf[8] = {v0.x, v0.y, v0.z, v0.w, v1.x, v1.y, v1.z, v1.w};
  unsigned short hh[8], ll[8];
  double pacc = 0.0;
#pragma unroll
  for (int j = 0; j < 8; j++) {
    hh[j] = f2bf(vf[j]);
    ll[j] = f2bf(vf[j] - bf2f(hh[j]));
    embT[(g * 8 + j) * NK + c] = vf[j];
    pacc = fma((double)vf[j], (double)vf[j], pacc);
  }
  uint4 hv, lv;
  hv.x = (unsigned)hh[0] | ((unsigned)hh[1] << 16); hv.y = (unsigned)hh[2] | ((unsigned)hh[3] << 16);
  hv.z = (unsigned)hh[4] | ((unsigned)hh[5] << 16); hv.w = (unsigned)hh[6] | ((unsigned)hh[7] << 16);
  lv.x = (unsigned)ll[0] | ((unsigned)ll[1] << 16); lv.y = (unsigned)ll[2] | ((unsigned)ll[3] << 16);
  lv.z = (unsigned)ll[4] | ((unsigned)ll[5] << 16); lv.w = (unsigned)ll[6] | ((unsigned)ll[7] << 16);
  int cg = c >> 5, cl = c & 31;
  int sw = (cl & 7) << 4;
  char* base = bp + cg * 16384 + cl * 512;
  *(uint4*)(base + ((g * 16) ^ sw)) = hv;
  *(uint4*)(base + 256 + ((g * 16) ^ sw)) = lv;
#pragma unroll
  for (int mask = 1; mask < 16; mask <<= 1) pacc += __shfl_xor(pacc, mask);
  if (g == 0) {
    en2d[c] = pacc;
    e2s[c] = (float)(pacc * 134217728.0 + 1073741824.0);  // e2*2^27 + 2^30
  }
}

// ---- main: MFMA bf16-split distance + u32-key argmin ----
// 1024 blocks x 256 thr (4 waves), 4 blocks/CU. BM=64 rows, 32 chunks of 32 codes.
// Wave tile 16 rows x 32 cols. A-frags in regs; B dbuf 2x16KB via global_load_lds.
__global__ __launch_bounds__(256, 4)
void argmin_k(const float* __restrict__ x, const char* __restrict__ bp,
              const float* __restrict__ e2s, int* __restrict__ idx_arr,
              float* __restrict__ out_idx, int* __restrict__ nflag,
              int* __restrict__ flags) {
  __shared__ __align__(16) char smem[32768];
  const int t    = threadIdx.x;
  const int lane = t & 63;
  const int w    = t >> 6;
  const int l15  = lane & 15;
  const int lo4  = lane >> 4;
  const int rbase = blockIdx.x * 64;

  // stage chunk 0 into buf0 (per-wave 4KB, linear)
  {
    const char* gsrc = bp + w * 4096 + lane * 16;
    char* ldst = smem + w * 4096;
#pragma unroll
    for (int u = 0; u < 4; u++) gload_lds16(gsrc + u * 1024, ldst + u * 1024);
  }

  // A-frags: global -> regs with in-reg bf16 hi/lo split (overlaps chunk-0 loads)
  short8 ah[4], al[4];
#pragma unroll
  for (int kk = 0; kk < 4; kk++) {
    const float* xp = &x[(rbase + w * 16 + l15) * 128 + kk * 32 + lo4 * 8];
    float4 v0 = *(const float4*)xp;
    float4 v1 = *(const float4*)(xp + 4);
    float vf[8] = {v0.x, v0.y, v0.z, v0.w, v1.x, v1.y, v1.z, v1.w};
    unsigned short hh[8], ll[8];
#pragma unroll
    for (int j = 0; j < 8; j++) {
      hh[j] = f2bf(vf[j]);
      ll[j] = f2bf(vf[j] - bf2f(hh[j]));
    }
    unsigned hu[4] = {(unsigned)hh[0] | ((unsigned)hh[1] << 16), (unsigned)hh[2] | ((unsigned)hh[3] << 16),
                      (unsigned)hh[4] | ((unsigned)hh[5] << 16), (unsigned)hh[6] | ((unsigned)hh[7] << 16)};
    unsigned lu[4] = {(unsigned)ll[0] | ((unsigned)ll[1] << 16), (unsigned)ll[2] | ((unsigned)ll[3] << 16),
                      (unsigned)ll[4] | ((unsigned)ll[5] << 16), (unsigned)ll[6] | ((unsigned)ll[7] << 16)};
    ah[kk] = *(short8*)hu;
    al[kk] = *(short8*)lu;
  }

  unsigned bv[4], b2[4];
#pragma unroll
  for (int r = 0; r < 4; r++) { bv[r] = 0xFFFFFFFFu; b2[r] = 0xFFFFFFFFu; }

  __syncthreads();   // chunk 0 resident

  int cur = 0;
  for (int cg = 0; cg < 32; cg++) {
    if (cg < 31) {
      const char* gsrc = bp + (cg + 1) * 16384 + w * 4096 + lane * 16;
      char* ldst = smem + (cur ^ 1) * 16384 + w * 4096;
#pragma unroll
      for (int u = 0; u < 4; u++) gload_lds16(gsrc + u * 1024, ldst + u * 1024);
    }

    float e2a = e2s[cg * 32 + l15];
    float e2b = e2s[cg * 32 + 16 + l15];

    f32x4 acc[2];
    acc[0] = (f32x4)(0.0f);
    acc[1] = (f32x4)(0.0f);

    const int bufb = cur * 16384;
#pragma unroll
    for (int kk = 0; kk < 4; kk++) {
      short8 bh[2], bl[2];
#pragma unroll
      for (int n = 0; n < 2; n++) {
        int code_l = n * 16 + l15;
        int sw = (code_l & 7) << 4;
        int byte_ = code_l * 512 + kk * 64 + (lo4 << 4);
        bh[n] = *(short8*)&smem[bufb + (byte_ ^ sw)];
        bl[n] = *(short8*)&smem[bufb + ((byte_ + 256) ^ sw)];
      }
#pragma unroll
      for (int n = 0; n < 2; n++) {
        acc[n] = __builtin_amdgcn_mfma_f32_16x16x32_bf16(ah[kk], bh[n], acc[n], 0, 0, 0);
        acc[n] = __builtin_amdgcn_mfma_f32_16x16x32_bf16(ah[kk], bl[n], acc[n], 0, 0, 0);
        acc[n] = __builtin_amdgcn_mfma_f32_16x16x32_bf16(al[kk], bh[n], acc[n], 0, 0, 0);
      }
    }

    // u32-key epilogue: key = (u32(e2s - 2^28*dot) & ~1023) | col
#pragma unroll
    for (int n = 0; n < 2; n++) {
      unsigned col = (unsigned)(cg * 32 + n * 16 + l15);
      float e2v = n ? e2b : e2a;
#pragma unroll
      for (int r = 0; r < 4; r++) {
        float ks = fmaf(acc[n][r], -268435456.0f, e2v);
        unsigned key = ((unsigned)ks & 0xFFFFFC00u) | col;
        unsigned old = bv[r];
        bv[r] = min(old, key);
        b2[r] = min(b2[r], max(old, key));
      }
    }

    __syncthreads();
    cur ^= 1;
  }

#pragma unroll
  for (int r = 0; r < 4; r++) {
    unsigned v = bv[r], v2 = b2[r];
    for (int mask = 1; mask < 16; mask <<= 1) {
      unsigned ov = __shfl_xor(v, mask);
      unsigned o2 = __shfl_xor(v2, mask);
      v2 = min(min(v2, o2), max(v, ov));
      v  = min(v, ov);
    }
    if (l15 == 0) {
      int row = rbase + w * 16 + lo4 * 4 + r;
      int ii = (int)(v & 1023u);
      idx_arr[row] = ii;
      out_idx[row] = (float)ii;
      if ((v2 >> 10) - (v >> 10) < 39u) {   // gap < 3e-4 in score units
        int p = atomicAdd(nflag, 1); flags[p] = row;
      }
    }
  }
}

// ---- exact f64 recompute for near-tie rows (coalesced via embT) ----
__global__ __launch_bounds__(256)
void fb_k(const float* __restrict__ x, const float* __restrict__ embT,
          const double* __restrict__ en2d, const int* __restrict__ nflag,
          const int* __restrict__ flags, int* __restrict__ idx_arr,
          float* __restrict__ out_idx) {
  int n = *nflag;
  __shared__ double xsh[DIM];
  __shared__ double sv[256];
  __shared__ int    si[256];
  int t = threadIdx.x;
  for (int f = blockIdx.x; f < n; f += gridDim.x) {
    int row = flags[f];
    __syncthreads();
    if (t < DIM) xsh[t] = (double)x[row * DIM + t];
    __syncthreads();
    double xe0 = 0.0, xe1 = 0.0, xe2 = 0.0, xe3 = 0.0;
#pragma unroll 4
    for (int d = 0; d < DIM; d++) {
      float4 v = *(const float4*)&embT[d * NK + t * 4];
      double xd = xsh[d];
      xe0 = fma((double)v.x, xd, xe0);
      xe1 = fma((double)v.y, xd, xe1);
      xe2 = fma((double)v.z, xd, xe2);
      xe3 = fma((double)v.w, xd, xe3);
    }
    double s0 = en2d[t * 4 + 0] - 2.0 * xe0;
    double s1 = en2d[t * 4 + 1] - 2.0 * xe1;
    double s2 = en2d[t * 4 + 2] - 2.0 * xe2;
    double s3 = en2d[t * 4 + 3] - 2.0 * xe3;
    double bvv = s0; int bii = t * 4;
    if (s1 < bvv) { bvv = s1; bii = t * 4 + 1; }
    if (s2 < bvv) { bvv = s2; bii = t * 4 + 2; }
    if (s3 < bvv) { bvv = s3; bii = t * 4 + 3; }
    sv[t] = bvv; si[t] = bii;
    __syncthreads();
    for (int sh = 128; sh > 0; sh >>= 1) {
      if (t < sh) {
        double ov = sv[t + sh]; int oi = si[t + sh];
        if (ov < sv[t] || (ov == sv[t] && oi < si[t])) { sv[t] = ov; si[t] = oi; }
      }
      __syncthreads();
    }
    if (t == 0) { idx_arr[row] = si[0]; out_idx[row] = (float)si[0]; }
  }
}

// ---- per-block histogram (LDS bins, plain stores — no global atomics) ----
__global__ void histb_k(const int* __restrict__ idx, unsigned* __restrict__ bcount) {
  __shared__ unsigned bins[NK];
  int t = threadIdx.x;
  for (int b = t; b < NK; b += 256) bins[b] = 0u;
  __syncthreads();
#pragma unroll
  for (int j = 0; j < 4; j++)
    atomicAdd(&bins[idx[blockIdx.x * 1024 + j * 256 + t]], 1u);
  __syncthreads();
  for (int b = t; b < NK; b += 256) bcount[blockIdx.x * NK + b] = bins[b];
}

// ---- totals + exclusive scan + per-block start cursors (atomic-free) ----
__global__ void scan_k(unsigned* __restrict__ bcount, unsigned* __restrict__ icounts,
                       unsigned* __restrict__ offsets) {
  __shared__ unsigned sc[NK];
  int t = threadIdx.x;
  unsigned tot = 0;
  for (int b = 0; b < 64; b++) tot += bcount[b * NK + t];
  icounts[t] = tot;
  sc[t] = tot;
  __syncthreads();
  for (int off = 1; off < NK; off <<= 1) {
    unsigned v = (t >= off) ? sc[t - off] : 0u;
    __syncthreads();
    sc[t] += v;
    __syncthreads();
  }
  unsigned excl = sc[t] - tot;
  offsets[t] = excl;
  unsigned run = excl;
  for (int b = 0; b < 64; b++) {
    unsigned c = bcount[b * NK + t];
    bcount[b * NK + t] = run;          // becomes per-block start
    run += c;
  }
}

// ---- scatter row ids (LDS cursors; no global atomics) ----
__global__ void scatter_k(const int* __restrict__ idx, const unsigned* __restrict__ bstart,
                          int* __restrict__ order) {
  __shared__ unsigned cur[NK];
  int t = threadIdx.x;
  for (int b = t; b < NK; b += 256) cur[b] = bstart[blockIdx.x * NK + b];
  __syncthreads();
#pragma unroll
  for (int j = 0; j < 4; j++) {
    int r = blockIdx.x * 1024 + j * 256 + t;
    unsigned p = atomicAdd(&cur[idx[r]], 1u);
    order[p] = r;
  }
}

// ---- fused gather: out_q, loss partials, dw_embed sums (no atomics; 4 rows in flight) ----
__global__ __launch_bounds__(512)
void fgather_k(const float* __restrict__ x, const float* __restrict__ emb,
               const unsigned* __restrict__ offsets, const unsigned* __restrict__ icounts,
               const int* __restrict__ order, float* __restrict__ out_q,
               float* __restrict__ dwsum, float* __restrict__ partial) {
  int k = blockIdx.x, t = threadIdx.x;
  int d = t & 127, h = t >> 7;   // h = 0..3
  float e = emb[k * DIM + d];
  unsigned s = offsets[k], cnt = icounts[k];
  float acc = 0.f, ls = 0.f;
  for (unsigned j = h; j < cnt; j += 4) {
    int row = order[s + j];
    float xv = x[row * DIM + d];
    out_q[row * DIM + d] = e;
    acc += xv;
    float dd = e - xv;
    ls += dd * dd;
  }
  __shared__ float sa[512], sl[512];
  sa[t] = acc; sl[t] = ls;
  __syncthreads();
  if (t < 128) dwsum[k * DIM + t] = sa[t] + sa[t + 128] + sa[t + 256] + sa[t + 384];
  for (int sh = 256; sh > 0; sh >>= 1) {
    if (t < sh) sl[t] += sl[t + sh];
    __syncthreads();
  }
  if (t == 0) partial[k] = sl[0];
}

// ---- loss + cluster-size EMA + csk ----
__global__ void fin_k(const float* __restrict__ cluster_size, const unsigned* __restrict__ icounts,
                      const float* __restrict__ partial, float* __restrict__ out_loss,
                      float* __restrict__ out_ncs, float* __restrict__ csk) {
  __shared__ float red[NK];
  int t = threadIdx.x;
  red[t] = partial[t];
  __syncthreads();
  for (int s = 512; s > 0; s >>= 1) {
    if (t < s) red[t] += red[t + s];
    __syncthreads();
  }
  float S = red[0];
  __syncthreads();
  if (t == 0) out_loss[0] = 2.0f * S / 8388608.0f;
  float ncs = cluster_size[t] * 0.99f + 0.01f * (float)icounts[t];
  out_ncs[t] = ncs;
  red[t] = ncs;
  __syncthreads();
  for (int s = 512; s > 0; s >>= 1) {
    if (t < s) red[t] += red[t + s];
    __syncthreads();
  }
  float n = red[0];
  csk[t] = (ncs + 1e-5f) / (n + 1024.0f * 1e-5f) * n;
}

// ---- embed_avg EMA + new embedding ----
__global__ void emb_k(const float* __restrict__ embed_avg, const float* __restrict__ dwsum,
                      const float* __restrict__ csk, float* __restrict__ out_nemb,
                      float* __restrict__ out_nea) {
  int i = blockIdx.x * 256 + threadIdx.x;
  float na = embed_avg[i] * 0.99f + 0.01f * dwsum[i];
  out_nea[i] = na;
  out_nemb[i] = na / csk[i >> 7];
}

extern "C" void kernel_launch(void* const* d_in, const int* in_sizes, int n_in,
                              void* d_out, int out_size, void* d_ws, size_t ws_size,
                              hipStream_t stream) {
  const float* x   = (const float*)d_in[0];
  const float* emb = (const float*)d_in[1];
  const float* cs  = (const float*)d_in[2];
  const float* ea  = (const float*)d_in[3];

  float* out      = (float*)d_out;
  float* out_q    = out;                      // [65536,128]
  float* out_loss = out + 8388608;            // scalar
  float* out_idx  = out + 8388609;            // [65536]
  float* out_nemb = out + 8454145;            // [1024,128]
  float* out_ncs  = out + 8585217;            // [1024]
  float* out_nea  = out + 8586241;            // [1024,128]

  float* W        = (float*)d_ws;
  float* e2s      = W;                              // [0,1024)
  double* en2d    = (double*)(W + 1024);            // [1024,3072)
  char*  bpack    = (char*)(W + 3072);              // [3072,134144) 512KB image
  float* dwsum    = W + 3072;                       // aliases bpack (dead after argmin)
  float* embT     = W + 134144;                     // [134144,265216) (dead after fb)
  unsigned* bcount = (unsigned*)(W + 134144);       // aliases embT lower: 64x1024
  int*   order    = (int*)(W + 199680);             // aliases embT upper: 65536
  float* partial  = W + 265216;                     // 1024
  unsigned* icounts = (unsigned*)(W + 266240);      // 1024
  unsigned* offsets = (unsigned*)(W + 267264);      // 1024
  float* csk      = W + 268288;                     // 1024
  int*   nflag    = (int*)(W + 269312);             // 1 (+pad)
  int*   flags    = (int*)(W + 269328);             // 65536
  int*   idx_arr  = (int*)(W + 334864);             // 65536

  bprep_k<<<64, 256, 0, stream>>>(emb, bpack, embT, e2s, en2d, nflag);
  argmin_k<<<1024, 256, 0, stream>>>(x, bpack, e2s, idx_arr, out_idx, nflag, flags);
  fb_k<<<1024, 256, 0, stream>>>(x, embT, en2d, nflag, flags, idx_arr, out_idx);
  histb_k<<<64, 256, 0, stream>>>(idx_arr, bcount);
  scan_k<<<1, 1024, 0, stream>>>(bcount, icounts, offsets);
  scatter_k<<<64, 256, 0, stream>>>(idx_arr, bcount, order);
  fgather_k<<<1024, 512, 0, stream>>>(x, emb, offsets, icounts, order, out_q, dwsum, partial);
  fin_k<<<1, 1024, 0, stream>>>(cs, icounts, partial, out_loss, out_ncs, csk);
  emb_k<<<512, 256, 0, stream>>>(ea, dwsum, csk, out_nemb, out_nea);
}